// Round 6
// baseline (597.727 us; speedup 1.0000x reference)
//
#include <hip/hip_runtime.h>
#include <math.h>

#define NB 8192
#define CC 256

// ---------------- K0: pack Wcat = [D1 | Wk_top | Wv_top | Wq]  (256 x 896) ----------------
// Wcat lives in d_out scratch (dead before final K7 write).
__global__ __launch_bounds__(256) void wpack(const float* __restrict__ D1,
                                             const float* __restrict__ Wk,
                                             const float* __restrict__ Wv,
                                             const float* __restrict__ Wq,
                                             float* __restrict__ Wcat) {
  int k = blockIdx.x;
  for (int j = threadIdx.x; j < 896; j += 256) {
    float v;
    if (j < 128)      v = D1[(size_t)k * 128 + j];
    else if (j < 384) v = Wk[(size_t)k * 256 + (j - 128)];
    else if (j < 640) v = Wv[(size_t)k * 256 + (j - 384)];
    else              v = Wq[(size_t)k * 256 + (j - 640)];
    Wcat[(size_t)k * 896 + j] = v;
  }
}

// ---------------- K1: transpose (B,C,N)->(B,N,C) + LayerNorm1 ----------------
__global__ __launch_bounds__(256) void k1_ln1(const float* __restrict__ features,
                                              const float* __restrict__ g1,
                                              const float* __restrict__ be1,
                                              float* __restrict__ X,
                                              float* __restrict__ F) {
  __shared__ float tile[256][36];
  int b = blockIdx.y;
  int n0 = blockIdx.x * 32;
  int t = threadIdx.x;
  int tn = t & 31, ch = t >> 5;
  for (int cb = 0; cb < 32; ++cb) {
    int c = cb * 8 + ch;
    tile[c][tn] = features[((size_t)b * 256 + c) * NB + n0 + tn];
  }
  __syncthreads();
  int tok = t >> 3, sub = t & 7;
  float s = 0.f, ss = 0.f;
  #pragma unroll
  for (int k = 0; k < 32; ++k) {
    float v = tile[sub + 8 * k][tok];
    s += v; ss += v * v;
  }
  #pragma unroll
  for (int m = 1; m < 8; m <<= 1) { s += __shfl_xor(s, m); ss += __shfl_xor(ss, m); }
  float mean = s * (1.f / 256.f);
  float var  = ss * (1.f / 256.f) - mean * mean;
  float rstd = rsqrtf(var + 1e-6f);
  size_t row = ((size_t)b * NB + n0 + tok) * 256;
  for (int k = 0; k < 32; ++k) {
    int c = sub + 8 * k;
    float v = tile[c][tok];
    F[row + c] = v;
    X[row + c] = (v - mean) * rstd * g1[c] + be1[c];
  }
}

// ---------------- generic tiled f32 GEMM 64x64, K-step 16 ----------------
// C[m,n] = act( A[m,:]@B[:,n] + bias[n] ) + resid[m,n]
// optional fused LayerNorm on A rows: a' = (a-mean)*rstd*lg[k]+lb[k]
__global__ __launch_bounds__(256) void gemm64(
    const float* __restrict__ A, int lda,
    const float* __restrict__ Bm, int ldb,
    float* __restrict__ Cc, int ldc,
    int K,
    const float* __restrict__ bias, int relu,
    const float* __restrict__ resid, int ldr,
    const float* __restrict__ mrs, const float* __restrict__ lg, const float* __restrict__ lb)
{
  __shared__ float As[16][68];
  __shared__ float Bs[16][68];
  int m0 = blockIdx.y * 64, n0 = blockIdx.x * 64;
  int t = threadIdx.x;
  int ty = t >> 4, tx = t & 15;
  float acc[4][4] = {{0.f,0.f,0.f,0.f},{0.f,0.f,0.f,0.f},{0.f,0.f,0.f,0.f},{0.f,0.f,0.f,0.f}};
  int ar = t >> 4, ak = t & 15;
  int bc = t & 63, bk0 = t >> 6;
  for (int k0 = 0; k0 < K; k0 += 16) {
    #pragma unroll
    for (int i = 0; i < 4; ++i) {
      int r = i * 16 + ar;
      float v = A[(size_t)(m0 + r) * lda + k0 + ak];
      if (mrs) {
        float mean = mrs[(m0 + r) * 2], rstd = mrs[(m0 + r) * 2 + 1];
        v = (v - mean) * rstd * lg[k0 + ak] + lb[k0 + ak];
      }
      As[ak][r] = v;
    }
    #pragma unroll
    for (int i = 0; i < 4; ++i) {
      int kk = i * 4 + bk0;
      Bs[kk][bc] = Bm[(size_t)(k0 + kk) * ldb + n0 + bc];
    }
    __syncthreads();
    #pragma unroll
    for (int kk = 0; kk < 16; ++kk) {
      float4 a4 = *(const float4*)&As[kk][ty * 4];
      float4 b4 = *(const float4*)&Bs[kk][tx * 4];
      float av[4] = {a4.x, a4.y, a4.z, a4.w};
      float bv[4] = {b4.x, b4.y, b4.z, b4.w};
      #pragma unroll
      for (int i = 0; i < 4; ++i)
        #pragma unroll
        for (int j = 0; j < 4; ++j)
          acc[i][j] += av[i] * bv[j];
    }
    __syncthreads();
  }
  #pragma unroll
  for (int i = 0; i < 4; ++i) {
    size_t m = m0 + ty * 4 + i;
    float vals[4];
    #pragma unroll
    for (int j = 0; j < 4; ++j) {
      float v = acc[i][j];
      if (bias) v += bias[n0 + tx * 4 + j];
      if (relu) v = fmaxf(v, 0.f);
      vals[j] = v;
    }
    if (resid) {
      float4 rv = *(const float4*)&resid[m * (size_t)ldr + n0 + tx * 4];
      vals[0] += rv.x; vals[1] += rv.y; vals[2] += rv.z; vals[3] += rv.w;
    }
    float4 o4; o4.x = vals[0]; o4.y = vals[1]; o4.z = vals[2]; o4.w = vals[3];
    *(float4*)&Cc[m * (size_t)ldc + n0 + tx * 4] = o4;
  }
}

// ---------------- K3: per-token gumbel-softmax selection + attention ----------------
// XC layout per row (896): [0:128)=x@D1, [128:384)=x@Wk_top, [384:640)=x@Wv_top, [640:896)=x@Wq
// d2s is stored XOR-swizzled: d2s[f*8 + (d ^ ((f>>3)&7))] = D2[f][d]
// so that 16 lanes (fg=f>>3) reading D2[f][d] spread across 8 banks (2-way = free).
__global__ __launch_bounds__(256) void k3_token(
    const float* __restrict__ XC,
    const int* __restrict__ edges,
    const float* __restrict__ gu,
    const float* __restrict__ xyz,
    const float* __restrict__ Wk, const float* __restrict__ Wv,
    const float* __restrict__ db1, const float* __restrict__ D2, const float* __restrict__ db2,
    float* __restrict__ O)
{
  __shared__ int   idxs[16];
  __shared__ float xyzg[16][3];
  __shared__ float xyzown[3];
  __shared__ float hbuf[16][8];
  __shared__ float wls[8][16];
  __shared__ float scw[8][3];
  __shared__ float d2s[1024];
  __shared__ float db1s[128];
  int b = blockIdx.y, n = blockIdx.x;
  int t = threadIdx.x;
  size_t bn = (size_t)b * NB + n;
  if (t < 16) idxs[t] = edges[((size_t)b * NB * 16 + (size_t)n * 16 + t) * 2];
  for (int i = t; i < 1024; i += 256) {
    int f = i >> 3, d = i & 7;
    d2s[f * 8 + (d ^ ((f >> 3) & 7))] = D2[i];
  }
  if (t < 128) db1s[t] = db1[t];
  if (t >= 128 && t < 131) xyzown[t - 128] = xyz[bn * 3 + (t - 128)];
  __syncthreads();
  if (t < 48) { int e = t / 3, j = t % 3; xyzg[e][j] = xyz[((size_t)b * NB + idxs[e]) * 3 + j]; }
  // --- h[e][d] = db2[d] + sum_f relu(xD[idx[e]][f]+db1[f]) * D2[f][d]
  {
    int e = t >> 4, fg = t & 15;
    int fgl = fg & 7;
    size_t rowE = ((size_t)b * NB + idxs[e]) * 896;
    const float4* xd4 = (const float4*)&XC[rowE + fg * 8];
    float4 A0 = xd4[0], A1 = xd4[1];
    float xv8[8] = {A0.x, A0.y, A0.z, A0.w, A1.x, A1.y, A1.z, A1.w};
    float acc[8] = {0.f,0.f,0.f,0.f,0.f,0.f,0.f,0.f};
    #pragma unroll
    for (int ff = 0; ff < 8; ++ff) {
      int f = fg * 8 + ff;
      float xv = fmaxf(xv8[ff] + db1s[f], 0.f);
      #pragma unroll
      for (int d = 0; d < 8; ++d) acc[d] += xv * d2s[f * 8 + (d ^ fgl)];
    }
    #pragma unroll
    for (int m = 1; m < 16; m <<= 1)
      #pragma unroll
      for (int d = 0; d < 8; ++d) acc[d] += __shfl_xor(acc[d], m);
    if (fg < 8) hbuf[e][fg] = acc[fg] + db2[fg];
  }
  __syncthreads();
  // --- gumbel softmax over EN per (d)
  if (t < 128) {
    int d = t >> 4, ee = t & 15;
    float lgt = hbuf[ee][d];
    float u = gu[(bn * 8 + d) * 16 + ee];
    float gn = -logf(-logf(u));
    float val = (lgt + gn) * 10.0f;   // 1/TAU = 10
    float mx = val;
    #pragma unroll
    for (int m = 1; m < 16; m <<= 1) mx = fmaxf(mx, __shfl_xor(mx, m));
    float ex = expf(val - mx);
    float sm = ex;
    #pragma unroll
    for (int m = 1; m < 16; m <<= 1) sm += __shfl_xor(sm, m);
    wls[d][ee] = ex / sm;
  }
  __syncthreads();
  if (t < 24) {
    int d = t / 3, j = t % 3;
    float s = 0.f;
    #pragma unroll
    for (int ee = 0; ee < 16; ++ee) s += wls[d][ee] * xyzg[ee][j];
    scw[d][j] = s - xyzown[j];   // sum(w)==1 makes this exact
  }
  __syncthreads();
  // --- k,v combine + attention, one channel per thread
  int c = t;
  size_t rowT = bn * 896;
  float qc = XC[rowT + 640 + c];
  float kk[8], vv[8];
  #pragma unroll
  for (int d = 0; d < 8; ++d) { kk[d] = 0.f; vv[d] = 0.f; }
  #pragma unroll
  for (int j = 0; j < 3; ++j) {
    float wkb = Wk[(size_t)(256 + j) * 256 + c];
    float wvb = Wv[(size_t)(256 + j) * 256 + c];
    #pragma unroll
    for (int d = 0; d < 8; ++d) { kk[d] += scw[d][j] * wkb; vv[d] += scw[d][j] * wvb; }
  }
  #pragma unroll 4
  for (int ee = 0; ee < 16; ++ee) {
    size_t rE = ((size_t)b * NB + idxs[ee]) * 896;
    float xk = XC[rE + 128 + c];
    float xv = XC[rE + 384 + c];
    #pragma unroll
    for (int d = 0; d < 8; ++d) { float w = wls[d][ee]; kk[d] += w * xk; vv[d] += w * xv; }
  }
  float sim[8];
  #pragma unroll
  for (int d = 0; d < 8; ++d) {
    float p = kk[d] * qc;
    #pragma unroll
    for (int m = 1; m < 32; m <<= 1) p += __shfl_xor(p, m);  // 32-lane head reduce
    sim[d] = p * 0.17677669529663687f; // 1/sqrt(32)
  }
  float mx = sim[0];
  #pragma unroll
  for (int d = 1; d < 8; ++d) mx = fmaxf(mx, sim[d]);
  float e8[8], sume = 0.f;
  #pragma unroll
  for (int d = 0; d < 8; ++d) { e8[d] = expf(sim[d] - mx); sume += e8[d]; }
  float inv = 1.f / sume;
  float oc = 0.f;
  #pragma unroll
  for (int d = 0; d < 8; ++d) oc += vv[d] * (e8[d] * inv);
  O[bn * 256 + c] = oc;
}

// ---------------- K5a: per-row mean/rstd for LN2 ----------------
__global__ __launch_bounds__(256) void k5a_stats(const float* __restrict__ F, float* __restrict__ MRS) {
  int wave = threadIdx.x >> 6, lane = threadIdx.x & 63;
  size_t row = (size_t)blockIdx.x * 4 + wave;
  float4 v4 = *(const float4*)&F[row * 256 + lane * 4];
  float s = v4.x + v4.y + v4.z + v4.w;
  float ss = v4.x * v4.x + v4.y * v4.y + v4.z * v4.z + v4.w * v4.w;
  #pragma unroll
  for (int m = 1; m < 64; m <<= 1) { s += __shfl_xor(s, m); ss += __shfl_xor(ss, m); }
  if (lane == 0) {
    float mean = s * (1.f / 256.f);
    float var = ss * (1.f / 256.f) - mean * mean;
    MRS[row * 2] = mean;
    MRS[row * 2 + 1] = rsqrtf(var + 1e-6f);
  }
}

// ---------------- K7: transpose (B,N,C) -> (B,C,N) ----------------
__global__ __launch_bounds__(256) void k7_transpose(const float* __restrict__ F, float* __restrict__ out) {
  __shared__ float tile[32][33];
  int b = blockIdx.z;
  int c0 = blockIdx.y * 32;
  int n0 = blockIdx.x * 32;
  int t = threadIdx.x;
  int nl = t >> 5, cl = t & 31;
  #pragma unroll
  for (int i = 0; i < 4; ++i) {
    int nn = nl + i * 8;
    tile[nn][cl] = F[((size_t)b * NB + n0 + nn) * 256 + c0 + cl];
  }
  __syncthreads();
  int cl2 = t >> 5, nl2 = t & 31;
  #pragma unroll
  for (int i = 0; i < 4; ++i) {
    int cc = cl2 + i * 8;
    out[((size_t)b * 256 + c0 + cc) * NB + n0 + nl2] = tile[nl2][cc];
  }
}

extern "C" void kernel_launch(void* const* d_in, const int* in_sizes, int n_in,
                              void* d_out, int out_size, void* d_ws, size_t ws_size,
                              hipStream_t stream) {
  const float* xyz      = (const float*)d_in[0];
  const float* features = (const float*)d_in[1];
  const int*   edges    = (const int*)d_in[2];
  const float* gu       = (const float*)d_in[3];
  const float* g1       = (const float*)d_in[4];
  const float* be1      = (const float*)d_in[5];
  const float* Wq       = (const float*)d_in[6];
  const float* Wk       = (const float*)d_in[7];
  const float* Wv       = (const float*)d_in[8];
  const float* Wo       = (const float*)d_in[9];
  const float* g2       = (const float*)d_in[10];
  const float* be2      = (const float*)d_in[11];
  const float* W1       = (const float*)d_in[12];
  const float* bf1      = (const float*)d_in[13];
  const float* W2       = (const float*)d_in[14];
  const float* bf2      = (const float*)d_in[15];
  const float* D1       = (const float*)d_in[16];
  const float* db1      = (const float*)d_in[17];
  const float* D2       = (const float*)d_in[18];
  const float* db2      = (const float*)d_in[19];
  float* out = (float*)d_out;
  float* ws  = (float*)d_ws;

  // ws layout (92.3 MB peak), all disjoint at time-of-use:
  float* X    = ws;                   // 16384 x 256  (x = LN1); dead after K2; reused as O
  float* F    = ws + 4194304;         // 16384 x 256  (feats_t -> feats2 -> feats_final, in-place)
  float* XC   = ws + 8388608;         // 16384 x 896  (xCat); dead after K3; first half reused as Y1
  float* O    = X;
  float* Y1   = XC;                   // 16384 x 512
  // d_out (4.19M floats) doubles as scratch for Wcat/MRS — both dead before K7 writes out.
  // (Round-2 bug: Wcat lived INSIDE XC's range; K2 read it while writing XC over it.)
  float* Wcat = out;                  // 256 x 896 = 229,376 floats
  float* MRS  = out + 229376;         // 16384 x 2 =  32,768 floats

  // K0: pack fused weight
  wpack<<<256, 256, 0, stream>>>(D1, Wk, Wv, Wq, Wcat);

  // K1: transpose + LN1
  k1_ln1<<<dim3(256, 2), 256, 0, stream>>>(features, g1, be1, X, F);

  // K2: xCat = x @ Wcat   (one launch, N=896)
  gemm64<<<dim3(14, 256), 256, 0, stream>>>(X, 256, Wcat, 896, XC, 896, 256, nullptr, 0, nullptr, 0, nullptr, nullptr, nullptr);

  // K3: per-token gumbel-softmax + attention -> O (pre-Wo)
  k3_token<<<dim3(8192, 2), 256, 0, stream>>>(XC, edges, gu, xyz, Wk, Wv, db1, D2, db2, O);

  // K4: feats2 = feats_t + O @ Wo   (in-place on F)
  gemm64<<<dim3(4, 256), 256, 0, stream>>>(O, 256, Wo, 256, F, 256, 256, nullptr, 0, F, 256, nullptr, nullptr, nullptr);

  // K5a: LN2 stats
  k5a_stats<<<4096, 256, 0, stream>>>(F, MRS);

  // K5b: Y1 = relu(LN2(feats2) @ W1 + bf1)
  gemm64<<<dim3(8, 256), 256, 0, stream>>>(F, 256, W1, 512, Y1, 512, 256, bf1, 1, nullptr, 0, MRS, g2, be2);

  // K6: feats = feats2 + Y1 @ W2 + bf2   (in-place on F)
  gemm64<<<dim3(4, 256), 256, 0, stream>>>(Y1, 512, W2, 256, F, 256, 512, bf2, 0, F, 256, nullptr, nullptr, nullptr);

  // K7: transpose to (B, C, N)
  k7_transpose<<<dim3(256, 8, 2), 256, 0, stream>>>(F, out);
}

// Round 8
// 533.521 us; speedup vs baseline: 1.1203x; 1.1203x over previous
//
#include <hip/hip_runtime.h>
#include <math.h>

#define NB 8192
#define CC 256

// ---------------- K0: pack Wcat = [D1 | Wk_top | Wv_top | Wq] (256x896) + bias row ----------------
// bias row (row 256): [db1 | 0...] so K2's GEMM folds db1 into xD (k3 then does relu(xD) directly).
__global__ __launch_bounds__(256) void wpack(const float* __restrict__ D1,
                                             const float* __restrict__ Wk,
                                             const float* __restrict__ Wv,
                                             const float* __restrict__ Wq,
                                             const float* __restrict__ db1,
                                             float* __restrict__ Wcat) {
  int k = blockIdx.x;
  for (int j = threadIdx.x; j < 896; j += 256) {
    float v;
    if (j < 128)      v = D1[(size_t)k * 128 + j];
    else if (j < 384) v = Wk[(size_t)k * 256 + (j - 128)];
    else if (j < 640) v = Wv[(size_t)k * 256 + (j - 384)];
    else              v = Wq[(size_t)k * 256 + (j - 640)];
    Wcat[(size_t)k * 896 + j] = v;
  }
  if (k == 0) {
    for (int j = threadIdx.x; j < 896; j += 256)
      Wcat[(size_t)256 * 896 + j] = (j < 128) ? db1[j] : 0.f;
  }
}

// ---------------- K1: transpose (B,C,N)->(B,N,C) + LayerNorm1 ----------------
__global__ __launch_bounds__(256) void k1_ln1(const float* __restrict__ features,
                                              const float* __restrict__ g1,
                                              const float* __restrict__ be1,
                                              float* __restrict__ X,
                                              float* __restrict__ F) {
  __shared__ float tile[256][36];
  int b = blockIdx.y;
  int n0 = blockIdx.x * 32;
  int t = threadIdx.x;
  int tn = t & 31, ch = t >> 5;
  for (int cb = 0; cb < 32; ++cb) {
    int c = cb * 8 + ch;
    tile[c][tn] = features[((size_t)b * 256 + c) * NB + n0 + tn];
  }
  __syncthreads();
  int tok = t >> 3, sub = t & 7;
  float s = 0.f, ss = 0.f;
  #pragma unroll
  for (int k = 0; k < 32; ++k) {
    float v = tile[sub + 8 * k][tok];
    s += v; ss += v * v;
  }
  #pragma unroll
  for (int m = 1; m < 8; m <<= 1) { s += __shfl_xor(s, m); ss += __shfl_xor(ss, m); }
  float mean = s * (1.f / 256.f);
  float var  = ss * (1.f / 256.f) - mean * mean;
  float rstd = rsqrtf(var + 1e-6f);
  size_t row = ((size_t)b * NB + n0 + tok) * 256;
  for (int k = 0; k < 32; ++k) {
    int c = sub + 8 * k;
    float v = tile[c][tok];
    F[row + c] = v;
    X[row + c] = (v - mean) * rstd * g1[c] + be1[c];
  }
}

// ---------------- gemm128: tiled f32 GEMM 128x128, K-step 16, 8x8 per thread ----------------
// C[m,n] = act( A[m,:]@B[:,n] + bias[n] ) + resid[m,n]; optional fused LN on A rows.
// Register tile is 2x2 quadrants of 4x4 (reads at ty*4 and 64+ty*4 -> broadcast/2-way LDS = free).
__global__ __launch_bounds__(256) void gemm128(
    const float* __restrict__ A, int lda,
    const float* __restrict__ Bm, int ldb,
    float* __restrict__ Cc, int ldc,
    int K,
    const float* __restrict__ bias, int relu,
    const float* __restrict__ resid, int ldr,
    const float* __restrict__ mrs, const float* __restrict__ lg, const float* __restrict__ lb)
{
  __shared__ __align__(16) float As[16][132];   // [k][m] (transposed on store)
  __shared__ __align__(16) float Bs[16][132];   // [k][n]
  int m0 = blockIdx.y * 128, n0 = blockIdx.x * 128;
  int t = threadIdx.x;
  int ty = t >> 4, tx = t & 15;
  float acc[2][2][4][4] = {};
  int ar  = t >> 2, ak4 = (t & 3) * 4;
  int bk  = t >> 5, bn4 = (t & 31) * 4;
  for (int k0 = 0; k0 < K; k0 += 16) {
    #pragma unroll
    for (int p = 0; p < 2; ++p) {
      int r = ar + 64 * p;
      float4 av = *(const float4*)&A[(size_t)(m0 + r) * lda + k0 + ak4];
      if (mrs) {
        float mean = mrs[(m0 + r) * 2], rstd = mrs[(m0 + r) * 2 + 1];
        av.x = (av.x - mean) * rstd * lg[k0 + ak4 + 0] + lb[k0 + ak4 + 0];
        av.y = (av.y - mean) * rstd * lg[k0 + ak4 + 1] + lb[k0 + ak4 + 1];
        av.z = (av.z - mean) * rstd * lg[k0 + ak4 + 2] + lb[k0 + ak4 + 2];
        av.w = (av.w - mean) * rstd * lg[k0 + ak4 + 3] + lb[k0 + ak4 + 3];
      }
      As[ak4 + 0][r] = av.x; As[ak4 + 1][r] = av.y;
      As[ak4 + 2][r] = av.z; As[ak4 + 3][r] = av.w;
    }
    #pragma unroll
    for (int p = 0; p < 2; ++p) {
      int kk = bk + 8 * p;
      *(float4*)&Bs[kk][bn4] = *(const float4*)&Bm[(size_t)(k0 + kk) * ldb + n0 + bn4];
    }
    __syncthreads();
    #pragma unroll
    for (int kk = 0; kk < 16; ++kk) {
      float4 a0 = *(const float4*)&As[kk][ty * 4];
      float4 a1 = *(const float4*)&As[kk][64 + ty * 4];
      float4 b0 = *(const float4*)&Bs[kk][tx * 4];
      float4 b1 = *(const float4*)&Bs[kk][64 + tx * 4];
      float am[2][4] = {{a0.x, a0.y, a0.z, a0.w}, {a1.x, a1.y, a1.z, a1.w}};
      float bv[2][4] = {{b0.x, b0.y, b0.z, b0.w}, {b1.x, b1.y, b1.z, b1.w}};
      #pragma unroll
      for (int h = 0; h < 2; ++h)
        #pragma unroll
        for (int g = 0; g < 2; ++g)
          #pragma unroll
          for (int i = 0; i < 4; ++i)
            #pragma unroll
            for (int j = 0; j < 4; ++j)
              acc[h][g][i][j] += am[h][i] * bv[g][j];
    }
    __syncthreads();
  }
  #pragma unroll
  for (int h = 0; h < 2; ++h)
    #pragma unroll
    for (int i = 0; i < 4; ++i) {
      size_t m = m0 + 64 * h + ty * 4 + i;
      #pragma unroll
      for (int g = 0; g < 2; ++g) {
        int nb = n0 + 64 * g + tx * 4;
        float vals[4];
        #pragma unroll
        for (int j = 0; j < 4; ++j) {
          float v = acc[h][g][i][j];
          if (bias) v += bias[nb + j];
          if (relu) v = fmaxf(v, 0.f);
          vals[j] = v;
        }
        if (resid) {
          float4 rv = *(const float4*)&resid[m * (size_t)ldr + nb];
          vals[0] += rv.x; vals[1] += rv.y; vals[2] += rv.z; vals[3] += rv.w;
        }
        float4 o4; o4.x = vals[0]; o4.y = vals[1]; o4.z = vals[2]; o4.w = vals[3];
        *(float4*)&Cc[m * (size_t)ldc + nb] = o4;
      }
    }
}

// ---------------- K3: wave-per-token gumbel-softmax + attention ----------------
// One 64-lane wave owns one token; 4 tokens per 256-thread block; no barriers after d2s preload.
// Lane layout: e = lane>>2 (edge 0..15), fq = lane&3 (f-quarter in h-phase; j=fq in xyz phase).
// kv phase: lane owns channels c = lane*4..lane*4+3; a HEAD (32 ch) spans 8 lanes, so the
// QK dot reduces with masks 1,2,4 ONLY (round-7 audit: masks up to 32 summed across heads = bug).
// d2s swizzle: store D2[f][d] at d2s[f*8 + (d ^ (f>>5))]; read with d ^ fq (f>>5 == fq in-range).
__global__ __launch_bounds__(256) void k3_wave(
    const float* __restrict__ XC,
    const int* __restrict__ edges,
    const float* __restrict__ gu,
    const float* __restrict__ xyz,
    const float* __restrict__ Wk, const float* __restrict__ Wv,
    const float* __restrict__ D2, const float* __restrict__ db2,
    float* __restrict__ O)
{
  __shared__ float d2s[1024];
  int t = threadIdx.x;
  for (int i = t; i < 1024; i += 256) {
    int f = i >> 3, d = i & 7;
    d2s[f * 8 + (d ^ (f >> 5))] = D2[i];
  }
  __syncthreads();

  int wv = t >> 6, lane = t & 63;
  int b = blockIdx.y;
  int n = blockIdx.x * 4 + wv;
  size_t bn = (size_t)b * NB + n;
  int e = lane >> 2, fq = lane & 3;

  int idx = edges[(bn * 16 + e) * 2];
  size_t rowE = ((size_t)b * NB + idx) * 896;

  // --- h-phase: h[e][d] = db2[d] + sum_f relu(xD[idx[e]][f]) * D2[f][d]  (db1 folded into K2)
  float acc[8] = {0.f, 0.f, 0.f, 0.f, 0.f, 0.f, 0.f, 0.f};
  const float4* xd4 = (const float4*)(XC + rowE + fq * 32);
  #pragma unroll
  for (int i = 0; i < 8; ++i) {
    float4 xd = xd4[i];
    float xv[4] = {fmaxf(xd.x, 0.f), fmaxf(xd.y, 0.f), fmaxf(xd.z, 0.f), fmaxf(xd.w, 0.f)};
    #pragma unroll
    for (int j = 0; j < 4; ++j) {
      int f = fq * 32 + i * 4 + j;
      #pragma unroll
      for (int d = 0; d < 8; ++d)
        acc[d] += xv[j] * d2s[f * 8 + (d ^ fq)];
    }
  }
  #pragma unroll
  for (int d = 0; d < 8; ++d) {
    acc[d] += __shfl_xor(acc[d], 1);
    acc[d] += __shfl_xor(acc[d], 2);   // all 4 fq-lanes now hold h[e][d] (pre-db2)
    acc[d] += db2[d];
  }

  // --- gumbel softmax over e (16 edges) per d; e lives in lane bits 2..5 (masks 4,8,16,32)
  float w[8];
  #pragma unroll
  for (int d = 0; d < 8; ++d) {
    float u = gu[(bn * 8 + d) * 16 + e];
    float gn = -logf(-logf(u));
    float val = (acc[d] + gn) * 10.0f;   // 1/TAU
    float mx = val;
    mx = fmaxf(mx, __shfl_xor(mx, 4));
    mx = fmaxf(mx, __shfl_xor(mx, 8));
    mx = fmaxf(mx, __shfl_xor(mx, 16));
    mx = fmaxf(mx, __shfl_xor(mx, 32));
    float ex = expf(val - mx);
    float sm = ex;
    sm += __shfl_xor(sm, 4);
    sm += __shfl_xor(sm, 8);
    sm += __shfl_xor(sm, 16);
    sm += __shfl_xor(sm, 32);
    w[d] = ex / sm;
  }

  // --- weighted xyz: scw[d][j] = sum_e w[d][e]*xyz[idx[e]][j] - xyz[own][j], lane's j = fq (fq<3)
  float xg = (fq < 3) ? xyz[((size_t)b * NB + idx) * 3 + fq] : 0.f;
  float xo = (fq < 3) ? xyz[bn * 3 + fq] : 0.f;
  float scw[8];
  #pragma unroll
  for (int d = 0; d < 8; ++d) {
    float s = w[d] * xg;
    s += __shfl_xor(s, 4);
    s += __shfl_xor(s, 8);
    s += __shfl_xor(s, 16);
    s += __shfl_xor(s, 32);
    scw[d] = s - xo;   // sum(w)==1 makes the -xyz fold exact
  }

  // --- k,v combine; lane owns channels c = lane*4..+3
  float4 kk[8], vv[8];
  #pragma unroll
  for (int d = 0; d < 8; ++d) {
    kk[d].x = kk[d].y = kk[d].z = kk[d].w = 0.f;
    vv[d].x = vv[d].y = vv[d].z = vv[d].w = 0.f;
  }
  #pragma unroll
  for (int j = 0; j < 3; ++j) {
    float4 wkb = *(const float4*)&Wk[(size_t)(256 + j) * 256 + lane * 4];
    float4 wvb = *(const float4*)&Wv[(size_t)(256 + j) * 256 + lane * 4];
    #pragma unroll
    for (int d = 0; d < 8; ++d) {
      float sc = __shfl(scw[d], (lane & ~3) | j);
      kk[d].x += sc * wkb.x; kk[d].y += sc * wkb.y; kk[d].z += sc * wkb.z; kk[d].w += sc * wkb.w;
      vv[d].x += sc * wvb.x; vv[d].y += sc * wvb.y; vv[d].z += sc * wvb.z; vv[d].w += sc * wvb.w;
    }
  }
  #pragma unroll 4
  for (int ee = 0; ee < 16; ++ee) {
    int eidx = __shfl(idx, ee * 4);
    size_t rE = ((size_t)b * NB + eidx) * 896;
    float4 xk = ((const float4*)(XC + rE + 128))[lane];
    float4 xv = ((const float4*)(XC + rE + 384))[lane];
    #pragma unroll
    for (int d = 0; d < 8; ++d) {
      float wd = __shfl(w[d], ee * 4);
      kk[d].x += wd * xk.x; kk[d].y += wd * xk.y; kk[d].z += wd * xk.z; kk[d].w += wd * xk.w;
      vv[d].x += wd * xv.x; vv[d].y += wd * xv.y; vv[d].z += wd * xv.z; vv[d].w += wd * xv.w;
    }
  }

  // --- attention: sim[d] per HEAD (8-lane group: masks 1,2,4); softmax over d; o = sum_d v*sm
  float4 q = ((const float4*)(XC + bn * 896 + 640))[lane];
  float sim[8];
  #pragma unroll
  for (int d = 0; d < 8; ++d) {
    float p = q.x * kk[d].x + q.y * kk[d].y + q.z * kk[d].z + q.w * kk[d].w;
    p += __shfl_xor(p, 1);
    p += __shfl_xor(p, 2);
    p += __shfl_xor(p, 4);   // head = lane>>3: reduce within the head's 8 lanes ONLY
    sim[d] = p * 0.17677669529663687f;   // 1/sqrt(32)
  }
  float mx = sim[0];
  #pragma unroll
  for (int d = 1; d < 8; ++d) mx = fmaxf(mx, sim[d]);
  float e8[8], sume = 0.f;
  #pragma unroll
  for (int d = 0; d < 8; ++d) { e8[d] = expf(sim[d] - mx); sume += e8[d]; }
  float inv = 1.f / sume;
  float4 oc; oc.x = oc.y = oc.z = oc.w = 0.f;
  #pragma unroll
  for (int d = 0; d < 8; ++d) {
    float sm = e8[d] * inv;
    oc.x += vv[d].x * sm; oc.y += vv[d].y * sm; oc.z += vv[d].z * sm; oc.w += vv[d].w * sm;
  }
  ((float4*)(O + bn * 256))[lane] = oc;
}

// ---------------- K5a: per-row mean/rstd for LN2 ----------------
__global__ __launch_bounds__(256) void k5a_stats(const float* __restrict__ F, float* __restrict__ MRS) {
  int wave = threadIdx.x >> 6, lane = threadIdx.x & 63;
  size_t row = (size_t)blockIdx.x * 4 + wave;
  float4 v4 = *(const float4*)&F[row * 256 + lane * 4];
  float s = v4.x + v4.y + v4.z + v4.w;
  float ss = v4.x * v4.x + v4.y * v4.y + v4.z * v4.z + v4.w * v4.w;
  #pragma unroll
  for (int m = 1; m < 64; m <<= 1) { s += __shfl_xor(s, m); ss += __shfl_xor(ss, m); }
  if (lane == 0) {
    float mean = s * (1.f / 256.f);
    float var = ss * (1.f / 256.f) - mean * mean;
    MRS[row * 2] = mean;
    MRS[row * 2 + 1] = rsqrtf(var + 1e-6f);
  }
}

// ---------------- K7: transpose (B,N,C) -> (B,C,N) ----------------
__global__ __launch_bounds__(256) void k7_transpose(const float* __restrict__ F, float* __restrict__ out) {
  __shared__ float tile[32][33];
  int b = blockIdx.z;
  int c0 = blockIdx.y * 32;
  int n0 = blockIdx.x * 32;
  int t = threadIdx.x;
  int nl = t >> 5, cl = t & 31;
  #pragma unroll
  for (int i = 0; i < 4; ++i) {
    int nn = nl + i * 8;
    tile[nn][cl] = F[((size_t)b * NB + n0 + nn) * 256 + c0 + cl];
  }
  __syncthreads();
  int cl2 = t >> 5, nl2 = t & 31;
  #pragma unroll
  for (int i = 0; i < 4; ++i) {
    int cc = cl2 + i * 8;
    out[((size_t)b * 256 + c0 + cc) * NB + n0 + nl2] = tile[nl2][cc];
  }
}

extern "C" void kernel_launch(void* const* d_in, const int* in_sizes, int n_in,
                              void* d_out, int out_size, void* d_ws, size_t ws_size,
                              hipStream_t stream) {
  const float* xyz      = (const float*)d_in[0];
  const float* features = (const float*)d_in[1];
  const int*   edges    = (const int*)d_in[2];
  const float* gu       = (const float*)d_in[3];
  const float* g1       = (const float*)d_in[4];
  const float* be1      = (const float*)d_in[5];
  const float* Wq       = (const float*)d_in[6];
  const float* Wk       = (const float*)d_in[7];
  const float* Wv       = (const float*)d_in[8];
  const float* Wo       = (const float*)d_in[9];
  const float* g2       = (const float*)d_in[10];
  const float* be2      = (const float*)d_in[11];
  const float* W1       = (const float*)d_in[12];
  const float* bf1      = (const float*)d_in[13];
  const float* W2       = (const float*)d_in[14];
  const float* bf2      = (const float*)d_in[15];
  const float* D1       = (const float*)d_in[16];
  const float* db1      = (const float*)d_in[17];
  const float* D2       = (const float*)d_in[18];
  const float* db2      = (const float*)d_in[19];
  float* out = (float*)d_out;
  float* ws  = (float*)d_ws;

  // ws layout (92.3 MB peak), all disjoint at time-of-use:
  float* X    = ws;                   // 16384 x 256  (x = LN1); dead after K2; reused as O
  float* F    = ws + 4194304;         // 16384 x 256  (feats_t -> feats2 -> feats_final, in-place)
  float* XC   = ws + 8388608;         // 16384 x 896  (xCat); dead after K3; first half reused as Y1
  float* O    = X;
  float* Y1   = XC;                   // 16384 x 512
  // d_out (4.19M floats) doubles as scratch for Wcat/bias/MRS — all dead before K7 writes out.
  float* Wcat = out;                  // 257 x 896 = 230,272 floats (row 256 = bias [db1|0])
  float* bcat = out + 229376;         // bias row
  float* MRS  = out + 230272;         // 16384 x 2 = 32,768 floats

  // K0: pack fused weight + bias row
  wpack<<<256, 256, 0, stream>>>(D1, Wk, Wv, Wq, db1, Wcat);

  // K1: transpose + LN1
  k1_ln1<<<dim3(256, 2), 256, 0, stream>>>(features, g1, be1, X, F);

  // K2: xCat = x @ Wcat + [db1|0]   (db1 folded here so k3 skips it)
  gemm128<<<dim3(7, 128), 256, 0, stream>>>(X, 256, Wcat, 896, XC, 896, 256, bcat, 0, nullptr, 0, nullptr, nullptr, nullptr);

  // K3: wave-per-token gumbel-softmax + attention -> O (pre-Wo)
  k3_wave<<<dim3(2048, 2), 256, 0, stream>>>(XC, edges, gu, xyz, Wk, Wv, D2, db2, O);

  // K4: feats2 = feats_t + O @ Wo   (in-place on F)
  gemm128<<<dim3(2, 128), 256, 0, stream>>>(O, 256, Wo, 256, F, 256, 256, nullptr, 0, F, 256, nullptr, nullptr, nullptr);

  // K5a: LN2 stats
  k5a_stats<<<4096, 256, 0, stream>>>(F, MRS);

  // K5b: Y1 = relu(LN2(feats2) @ W1 + bf1)
  gemm128<<<dim3(4, 128), 256, 0, stream>>>(F, 256, W1, 512, Y1, 512, 256, bf1, 1, nullptr, 0, MRS, g2, be2);

  // K6: feats = feats2 + Y1 @ W2 + bf2   (in-place on F)
  gemm128<<<dim3(2, 128), 256, 0, stream>>>(Y1, 512, W2, 256, F, 256, 512, bf2, 0, F, 256, nullptr, nullptr, nullptr);

  // K7: transpose to (B, C, N)
  k7_transpose<<<dim3(256, 8, 2), 256, 0, stream>>>(F, out);
}

// Round 11
// 379.321 us; speedup vs baseline: 1.5758x; 1.4065x over previous
//
#include <hip/hip_runtime.h>
#include <math.h>

#define NB 8192
#define CC 256

using bf16x8 = __attribute__((ext_vector_type(8))) short;
using f32x4  = __attribute__((ext_vector_type(4))) float;

__device__ inline ushort f2b(float f) {   // f32 -> bf16 RNE
  union { float f; unsigned u; } v; v.f = f;
  unsigned u = v.u;
  u += 0x7FFF + ((u >> 16) & 1);
  return (ushort)(u >> 16);
}

// ---------------- K0: pack W^T as bf16 into d_out scratch ----------------
// WtKVQ[768][256] = [Wk_top|Wv_top|Wq]^T ; WtO[256][256]=Wo^T ; Wt1[512][256]=W1^T ; Wt2[256][512]=W2^T
__global__ __launch_bounds__(256) void wpackT(const float* __restrict__ Wk, const float* __restrict__ Wv,
                                              const float* __restrict__ Wq, const float* __restrict__ Wo,
                                              const float* __restrict__ W1, const float* __restrict__ W2,
                                              ushort* __restrict__ WtKVQ, ushort* __restrict__ WtO,
                                              ushort* __restrict__ Wt1, ushort* __restrict__ Wt2) {
  int i = blockIdx.x * 256 + threadIdx.x;
  if (i < 196608) {
    int n = i >> 8, k = i & 255;
    float v = (n < 256) ? Wk[(size_t)k * 256 + n]
            : (n < 512) ? Wv[(size_t)k * 256 + (n - 256)]
                        : Wq[(size_t)k * 256 + (n - 512)];
    WtKVQ[(size_t)n * 256 + k] = f2b(v);
  } else if (i < 262144) {
    int j = i - 196608; int n = j >> 8, k = j & 255;
    WtO[(size_t)n * 256 + k] = f2b(Wo[(size_t)k * 256 + n]);
  } else if (i < 393216) {
    int j = i - 262144; int n = j >> 8, k = j & 255;   // n 0..511
    Wt1[(size_t)n * 256 + k] = f2b(W1[(size_t)k * 512 + n]);
  } else {
    int j = i - 393216; int n = j >> 9, k = j & 511;   // n 0..255, k 0..511
    Wt2[(size_t)n * 512 + k] = f2b(W2[(size_t)k * 256 + n]);
  }
}

// ---------------- K1: transpose (B,C,N)->(B,N,C) + LayerNorm1 ----------------
__global__ __launch_bounds__(256) void k1_ln1(const float* __restrict__ features,
                                              const float* __restrict__ g1,
                                              const float* __restrict__ be1,
                                              float* __restrict__ X,
                                              float* __restrict__ F) {
  __shared__ float tile[256][36];
  int b = blockIdx.y;
  int n0 = blockIdx.x * 32;
  int t = threadIdx.x;
  int tn = t & 31, ch = t >> 5;
  for (int cb = 0; cb < 32; ++cb) {
    int c = cb * 8 + ch;
    tile[c][tn] = features[((size_t)b * 256 + c) * NB + n0 + tn];
  }
  __syncthreads();
  int tok = t >> 3, sub = t & 7;
  float s = 0.f, ss = 0.f;
  #pragma unroll
  for (int k = 0; k < 32; ++k) {
    float v = tile[sub + 8 * k][tok];
    s += v; ss += v * v;
  }
  #pragma unroll
  for (int m = 1; m < 8; m <<= 1) { s += __shfl_xor(s, m); ss += __shfl_xor(ss, m); }
  float mean = s * (1.f / 256.f);
  float var  = ss * (1.f / 256.f) - mean * mean;
  float rstd = rsqrtf(var + 1e-6f);
  size_t row = ((size_t)b * NB + n0 + tok) * 256;
  for (int k = 0; k < 32; ++k) {
    int c = sub + 8 * k;
    float v = tile[c][tok];
    F[row + c] = v;
    X[row + c] = (v - mean) * rstd * g1[c] + be1[c];
  }
}

// ---------------- gemm128: f32 VALU GEMM (kept ONLY for the precision-critical xD) ----------------
__global__ __launch_bounds__(256) void gemm128(
    const float* __restrict__ A, int lda,
    const float* __restrict__ Bm, int ldb,
    float* __restrict__ Cc, int ldc,
    int K,
    const float* __restrict__ bias, int relu,
    const float* __restrict__ resid, int ldr,
    const float* __restrict__ mrs, const float* __restrict__ lg, const float* __restrict__ lb)
{
  __shared__ __align__(16) float As[16][132];
  __shared__ __align__(16) float Bs[16][132];
  int m0 = blockIdx.y * 128, n0 = blockIdx.x * 128;
  int t = threadIdx.x;
  int ty = t >> 4, tx = t & 15;
  float acc[2][2][4][4] = {};
  int ar  = t >> 2, ak4 = (t & 3) * 4;
  int bk  = t >> 5, bn4 = (t & 31) * 4;
  for (int k0 = 0; k0 < K; k0 += 16) {
    #pragma unroll
    for (int p = 0; p < 2; ++p) {
      int r = ar + 64 * p;
      float4 av = *(const float4*)&A[(size_t)(m0 + r) * lda + k0 + ak4];
      if (mrs) {
        float mean = mrs[(m0 + r) * 2], rstd = mrs[(m0 + r) * 2 + 1];
        av.x = (av.x - mean) * rstd * lg[k0 + ak4 + 0] + lb[k0 + ak4 + 0];
        av.y = (av.y - mean) * rstd * lg[k0 + ak4 + 1] + lb[k0 + ak4 + 1];
        av.z = (av.z - mean) * rstd * lg[k0 + ak4 + 2] + lb[k0 + ak4 + 2];
        av.w = (av.w - mean) * rstd * lg[k0 + ak4 + 3] + lb[k0 + ak4 + 3];
      }
      As[ak4 + 0][r] = av.x; As[ak4 + 1][r] = av.y;
      As[ak4 + 2][r] = av.z; As[ak4 + 3][r] = av.w;
    }
    #pragma unroll
    for (int p = 0; p < 2; ++p) {
      int kk = bk + 8 * p;
      *(float4*)&Bs[kk][bn4] = *(const float4*)&Bm[(size_t)(k0 + kk) * ldb + n0 + bn4];
    }
    __syncthreads();
    #pragma unroll
    for (int kk = 0; kk < 16; ++kk) {
      float4 a0 = *(const float4*)&As[kk][ty * 4];
      float4 a1 = *(const float4*)&As[kk][64 + ty * 4];
      float4 b0 = *(const float4*)&Bs[kk][tx * 4];
      float4 b1 = *(const float4*)&Bs[kk][64 + tx * 4];
      float am[2][4] = {{a0.x, a0.y, a0.z, a0.w}, {a1.x, a1.y, a1.z, a1.w}};
      float bv[2][4] = {{b0.x, b0.y, b0.z, b0.w}, {b1.x, b1.y, b1.z, b1.w}};
      #pragma unroll
      for (int h = 0; h < 2; ++h)
        #pragma unroll
        for (int g = 0; g < 2; ++g)
          #pragma unroll
          for (int i = 0; i < 4; ++i)
            #pragma unroll
            for (int j = 0; j < 4; ++j)
              acc[h][g][i][j] += am[h][i] * bv[g][j];
    }
    __syncthreads();
  }
  #pragma unroll
  for (int h = 0; h < 2; ++h)
    #pragma unroll
    for (int i = 0; i < 4; ++i) {
      size_t m = m0 + 64 * h + ty * 4 + i;
      #pragma unroll
      for (int g = 0; g < 2; ++g) {
        int nb = n0 + 64 * g + tx * 4;
        float vals[4];
        #pragma unroll
        for (int j = 0; j < 4; ++j) {
          float v = acc[h][g][i][j];
          if (bias) v += bias[nb + j];
          if (relu) v = fmaxf(v, 0.f);
          vals[j] = v;
        }
        if (resid) {
          float4 rv = *(const float4*)&resid[m * (size_t)ldr + nb];
          vals[0] += rv.x; vals[1] += rv.y; vals[2] += rv.z; vals[3] += rv.w;
        }
        float4 o4; o4.x = vals[0]; o4.y = vals[1]; o4.z = vals[2]; o4.w = vals[3];
        *(float4*)&Cc[m * (size_t)ldc + nb] = o4;
      }
    }
}

// ---------------- gemm_mfma: bf16 MFMA GEMM, 128x128 tile, 4 waves (2x2 of 64x64) ----------------
// A f32 [M][K] (optional fused LN), staged->bf16 LDS [m][32k]; Bt = W^T bf16 [N][K] -> LDS [n][32k].
// XOR swizzle kq^=(row>>1)&3 on both store and read: 16-lane frag reads are 2-way (free, m136).
// mfma_f32_16x16x32_bf16: A lane: row=l&15, k=8*(l>>4)+j ; C/D: col=l&15, row=4*(l>>4)+r (m89).
// As/Bs MUST be 16B-aligned: accessed via uint4/bf16x8 vectors (r9 audit: ushort default align=2).
__global__ __launch_bounds__(256) void gemm_mfma(
    const float* __restrict__ A, int lda,
    const ushort* __restrict__ Bt,
    float* __restrict__ Cc, int ldc,
    int K,
    const float* __restrict__ bias, int relu,
    const float* __restrict__ resid, int ldr,
    const float* __restrict__ mrs, const float* __restrict__ lg, const float* __restrict__ lb)
{
  __shared__ __align__(16) ushort As[128 * 32];
  __shared__ __align__(16) ushort Bs[128 * 32];
  int t = threadIdx.x;
  int m0 = blockIdx.y * 128, n0 = blockIdx.x * 128;
  int wv = t >> 6, lane = t & 63;
  int wm = wv >> 1, wn = wv & 1;
  int lr = lane & 15, kg = lane >> 4;
  f32x4 acc[4][4];
  #pragma unroll
  for (int i = 0; i < 4; ++i)
    #pragma unroll
    for (int j = 0; j < 4; ++j)
      acc[i][j] = (f32x4)0.0f;

  for (int k0 = 0; k0 < K; k0 += 32) {
    // stage A (f32 -> bf16), 2 chunks of 8 elems per thread
    #pragma unroll
    for (int p = 0; p < 2; ++p) {
      int c = t + p * 256;
      int m = c >> 2, kq = c & 3;
      const float* src = &A[(size_t)(m0 + m) * lda + k0 + kq * 8];
      float v[8];
      *(float4*)&v[0] = *(const float4*)src;
      *(float4*)&v[4] = *(const float4*)(src + 4);
      if (mrs) {
        float mean = mrs[(m0 + m) * 2], rstd = mrs[(m0 + m) * 2 + 1];
        #pragma unroll
        for (int j = 0; j < 8; ++j) {
          int kk = k0 + kq * 8 + j;
          v[j] = (v[j] - mean) * rstd * lg[kk] + lb[kk];
        }
      }
      ushort o[8];
      #pragma unroll
      for (int j = 0; j < 8; ++j) o[j] = f2b(v[j]);
      *(uint4*)&As[m * 32 + (kq ^ ((m >> 1) & 3)) * 8] = *(uint4*)o;
    }
    // stage B (already bf16)
    #pragma unroll
    for (int p = 0; p < 2; ++p) {
      int c = t + p * 256;
      int n = c >> 2, kq = c & 3;
      uint4 w = *(const uint4*)&Bt[(size_t)(n0 + n) * K + k0 + kq * 8];
      *(uint4*)&Bs[n * 32 + (kq ^ ((n >> 1) & 3)) * 8] = w;
    }
    __syncthreads();
    bf16x8 af[4], bfr[4];
    #pragma unroll
    for (int mi = 0; mi < 4; ++mi) {
      int m = wm * 64 + mi * 16 + lr;
      af[mi] = *(const bf16x8*)&As[m * 32 + (kg ^ ((m >> 1) & 3)) * 8];
    }
    #pragma unroll
    for (int ni = 0; ni < 4; ++ni) {
      int n = wn * 64 + ni * 16 + lr;
      bfr[ni] = *(const bf16x8*)&Bs[n * 32 + (kg ^ ((n >> 1) & 3)) * 8];
    }
    #pragma unroll
    for (int mi = 0; mi < 4; ++mi)
      #pragma unroll
      for (int ni = 0; ni < 4; ++ni)
        acc[mi][ni] = __builtin_amdgcn_mfma_f32_16x16x32_bf16(af[mi], bfr[ni], acc[mi][ni], 0, 0, 0);
    __syncthreads();
  }
  // epilogue: col = n0+wn*64+ni*16+lr ; row = m0+wm*64+mi*16+kg*4+r
  #pragma unroll
  for (int ni = 0; ni < 4; ++ni) {
    int col = n0 + wn * 64 + ni * 16 + lr;
    float bv = bias ? bias[col] : 0.f;
    #pragma unroll
    for (int mi = 0; mi < 4; ++mi) {
      #pragma unroll
      for (int r = 0; r < 4; ++r) {
        int row = m0 + wm * 64 + mi * 16 + kg * 4 + r;
        float v = acc[mi][ni][r] + bv;
        if (relu) v = fmaxf(v, 0.f);
        if (resid) v += resid[(size_t)row * ldr + col];
        Cc[(size_t)row * ldc + col] = v;
      }
    }
  }
}

// ---------------- K3: wave-per-token gumbel-softmax + attention (unchanged from r8, passed) ----------------
__global__ __launch_bounds__(256) void k3_wave(
    const float* __restrict__ XC,
    const int* __restrict__ edges,
    const float* __restrict__ gu,
    const float* __restrict__ xyz,
    const float* __restrict__ Wk, const float* __restrict__ Wv,
    const float* __restrict__ D2, const float* __restrict__ db2,
    float* __restrict__ O)
{
  __shared__ float d2s[1024];
  int t = threadIdx.x;
  for (int i = t; i < 1024; i += 256) {
    int f = i >> 3, d = i & 7;
    d2s[f * 8 + (d ^ (f >> 5))] = D2[i];
  }
  __syncthreads();

  int wv = t >> 6, lane = t & 63;
  int b = blockIdx.y;
  int n = blockIdx.x * 4 + wv;
  size_t bn = (size_t)b * NB + n;
  int e = lane >> 2, fq = lane & 3;

  int idx = edges[(bn * 16 + e) * 2];
  size_t rowE = ((size_t)b * NB + idx) * 896;

  float acc[8] = {0.f, 0.f, 0.f, 0.f, 0.f, 0.f, 0.f, 0.f};
  const float4* xd4 = (const float4*)(XC + rowE + fq * 32);
  #pragma unroll
  for (int i = 0; i < 8; ++i) {
    float4 xd = xd4[i];
    float xv[4] = {fmaxf(xd.x, 0.f), fmaxf(xd.y, 0.f), fmaxf(xd.z, 0.f), fmaxf(xd.w, 0.f)};
    #pragma unroll
    for (int j = 0; j < 4; ++j) {
      int f = fq * 32 + i * 4 + j;
      #pragma unroll
      for (int d = 0; d < 8; ++d)
        acc[d] += xv[j] * d2s[f * 8 + (d ^ fq)];
    }
  }
  #pragma unroll
  for (int d = 0; d < 8; ++d) {
    acc[d] += __shfl_xor(acc[d], 1);
    acc[d] += __shfl_xor(acc[d], 2);
    acc[d] += db2[d];
  }

  float w[8];
  #pragma unroll
  for (int d = 0; d < 8; ++d) {
    float u = gu[(bn * 8 + d) * 16 + e];
    float gn = -logf(-logf(u));
    float val = (acc[d] + gn) * 10.0f;
    float mx = val;
    mx = fmaxf(mx, __shfl_xor(mx, 4));
    mx = fmaxf(mx, __shfl_xor(mx, 8));
    mx = fmaxf(mx, __shfl_xor(mx, 16));
    mx = fmaxf(mx, __shfl_xor(mx, 32));
    float ex = expf(val - mx);
    float sm = ex;
    sm += __shfl_xor(sm, 4);
    sm += __shfl_xor(sm, 8);
    sm += __shfl_xor(sm, 16);
    sm += __shfl_xor(sm, 32);
    w[d] = ex / sm;
  }

  float xg = (fq < 3) ? xyz[((size_t)b * NB + idx) * 3 + fq] : 0.f;
  float xo = (fq < 3) ? xyz[bn * 3 + fq] : 0.f;
  float scw[8];
  #pragma unroll
  for (int d = 0; d < 8; ++d) {
    float s = w[d] * xg;
    s += __shfl_xor(s, 4);
    s += __shfl_xor(s, 8);
    s += __shfl_xor(s, 16);
    s += __shfl_xor(s, 32);
    scw[d] = s - xo;
  }

  float4 kk[8], vv[8];
  #pragma unroll
  for (int d = 0; d < 8; ++d) {
    kk[d].x = kk[d].y = kk[d].z = kk[d].w = 0.f;
    vv[d].x = vv[d].y = vv[d].z = vv[d].w = 0.f;
  }
  #pragma unroll
  for (int j = 0; j < 3; ++j) {
    float4 wkb = *(const float4*)&Wk[(size_t)(256 + j) * 256 + lane * 4];
    float4 wvb = *(const float4*)&Wv[(size_t)(256 + j) * 256 + lane * 4];
    #pragma unroll
    for (int d = 0; d < 8; ++d) {
      float sc = __shfl(scw[d], (lane & ~3) | j);
      kk[d].x += sc * wkb.x; kk[d].y += sc * wkb.y; kk[d].z += sc * wkb.z; kk[d].w += sc * wkb.w;
      vv[d].x += sc * wvb.x; vv[d].y += sc * wvb.y; vv[d].z += sc * wvb.z; vv[d].w += sc * wvb.w;
    }
  }
  #pragma unroll 4
  for (int ee = 0; ee < 16; ++ee) {
    int eidx = __shfl(idx, ee * 4);
    size_t rE = ((size_t)b * NB + eidx) * 896;
    float4 xk = ((const float4*)(XC + rE + 128))[lane];
    float4 xv = ((const float4*)(XC + rE + 384))[lane];
    #pragma unroll
    for (int d = 0; d < 8; ++d) {
      float wd = __shfl(w[d], ee * 4);
      kk[d].x += wd * xk.x; kk[d].y += wd * xk.y; kk[d].z += wd * xk.z; kk[d].w += wd * xk.w;
      vv[d].x += wd * xv.x; vv[d].y += wd * xv.y; vv[d].z += wd * xv.z; vv[d].w += wd * xv.w;
    }
  }

  float4 q = ((const float4*)(XC + bn * 896 + 640))[lane];
  float sim[8];
  #pragma unroll
  for (int d = 0; d < 8; ++d) {
    float p = q.x * kk[d].x + q.y * kk[d].y + q.z * kk[d].z + q.w * kk[d].w;
    p += __shfl_xor(p, 1);
    p += __shfl_xor(p, 2);
    p += __shfl_xor(p, 4);   // head = 8 lanes only
    sim[d] = p * 0.17677669529663687f;
  }
  float mx = sim[0];
  #pragma unroll
  for (int d = 1; d < 8; ++d) mx = fmaxf(mx, sim[d]);
  float e8[8], sume = 0.f;
  #pragma unroll
  for (int d = 0; d < 8; ++d) { e8[d] = expf(sim[d] - mx); sume += e8[d]; }
  float inv = 1.f / sume;
  float4 oc; oc.x = oc.y = oc.z = oc.w = 0.f;
  #pragma unroll
  for (int d = 0; d < 8; ++d) {
    float sm = e8[d] * inv;
    oc.x += vv[d].x * sm; oc.y += vv[d].y * sm; oc.z += vv[d].z * sm; oc.w += vv[d].w * sm;
  }
  ((float4*)(O + bn * 256))[lane] = oc;
}

// ---------------- K5a: per-row mean/rstd for LN2 ----------------
__global__ __launch_bounds__(256) void k5a_stats(const float* __restrict__ F, float* __restrict__ MRS) {
  int wave = threadIdx.x >> 6, lane = threadIdx.x & 63;
  size_t row = (size_t)blockIdx.x * 4 + wave;
  float4 v4 = *(const float4*)&F[row * 256 + lane * 4];
  float s = v4.x + v4.y + v4.z + v4.w;
  float ss = v4.x * v4.x + v4.y * v4.y + v4.z * v4.z + v4.w * v4.w;
  #pragma unroll
  for (int m = 1; m < 64; m <<= 1) { s += __shfl_xor(s, m); ss += __shfl_xor(ss, m); }
  if (lane == 0) {
    float mean = s * (1.f / 256.f);
    float var = ss * (1.f / 256.f) - mean * mean;
    MRS[row * 2] = mean;
    MRS[row * 2 + 1] = rsqrtf(var + 1e-6f);
  }
}

// ---------------- K7: transpose (B,N,C) -> (B,C,N) ----------------
__global__ __launch_bounds__(256) void k7_transpose(const float* __restrict__ F, float* __restrict__ out) {
  __shared__ float tile[32][33];
  int b = blockIdx.z;
  int c0 = blockIdx.y * 32;
  int n0 = blockIdx.x * 32;
  int t = threadIdx.x;
  int nl = t >> 5, cl = t & 31;
  #pragma unroll
  for (int i = 0; i < 4; ++i) {
    int nn = nl + i * 8;
    tile[nn][cl] = F[((size_t)b * NB + n0 + nn) * 256 + c0 + cl];
  }
  __syncthreads();
  int cl2 = t >> 5, nl2 = t & 31;
  #pragma unroll
  for (int i = 0; i < 4; ++i) {
    int cc = cl2 + i * 8;
    out[((size_t)b * 256 + c0 + cc) * NB + n0 + nl2] = tile[nl2][cc];
  }
}

extern "C" void kernel_launch(void* const* d_in, const int* in_sizes, int n_in,
                              void* d_out, int out_size, void* d_ws, size_t ws_size,
                              hipStream_t stream) {
  const float* xyz      = (const float*)d_in[0];
  const float* features = (const float*)d_in[1];
  const int*   edges    = (const int*)d_in[2];
  const float* gu       = (const float*)d_in[3];
  const float* g1       = (const float*)d_in[4];
  const float* be1      = (const float*)d_in[5];
  const float* Wq       = (const float*)d_in[6];
  const float* Wk       = (const float*)d_in[7];
  const float* Wv       = (const float*)d_in[8];
  const float* Wo       = (const float*)d_in[9];
  const float* g2       = (const float*)d_in[10];
  const float* be2      = (const float*)d_in[11];
  const float* W1       = (const float*)d_in[12];
  const float* bf1      = (const float*)d_in[13];
  const float* W2       = (const float*)d_in[14];
  const float* bf2      = (const float*)d_in[15];
  const float* D1       = (const float*)d_in[16];
  const float* db1      = (const float*)d_in[17];
  const float* D2       = (const float*)d_in[18];
  const float* db2      = (const float*)d_in[19];
  float* out = (float*)d_out;
  float* ws  = (float*)d_ws;

  // ws layout (92.3 MB peak), all disjoint at time-of-use:
  float* X    = ws;                   // 16384 x 256 f32 (LN1 out); dead after K2; reused as O
  float* F    = ws + 4194304;         // 16384 x 256 (feats_t -> feats2 -> final, in-place)
  float* XC   = ws + 8388608;         // 16384 x 896 (xCat); dead after K3; reused as Y1
  float* O    = X;
  float* Y1   = XC;                   // 16384 x 512
  // d_out (16.8 MB) as scratch: bf16 W^T pack (1 MB) + MRS — all dead before K7 writes out.
  ushort* WtKVQ = (ushort*)out;       // 768x256 bf16
  ushort* WtO   = WtKVQ + 196608;     // 256x256
  ushort* Wt1   = WtO + 65536;        // 512x256
  ushort* Wt2   = Wt1 + 131072;       // 256x512  (ends at 524288 ushort = 262144 f32 slots)
  float*  MRS   = out + 262144;       // 16384 x 2

  // K0: pack bf16 transposed weights
  wpackT<<<2048, 256, 0, stream>>>(Wk, Wv, Wq, Wo, W1, W2, WtKVQ, WtO, Wt1, Wt2);

  // K1: transpose + LN1
  k1_ln1<<<dim3(256, 2), 256, 0, stream>>>(features, g1, be1, X, F);

  // K2a: xD = X @ D1 + db1  (f32 — gumbel-logit path has x10 amplification, keep precise)
  gemm128<<<dim3(1, 128), 256, 0, stream>>>(X, 256, D1, 128, XC, 896, 256, db1, 0, nullptr, 0, nullptr, nullptr, nullptr);

  // K2b: [xK|xV|xQ] = X @ [Wk_top|Wv_top|Wq]  (bf16 MFMA)
  gemm_mfma<<<dim3(6, 128), 256, 0, stream>>>(X, 256, WtKVQ, XC + 128, 896, 256, nullptr, 0, nullptr, 0, nullptr, nullptr, nullptr);

  // K3: wave-per-token gumbel-softmax + attention -> O (pre-Wo)
  k3_wave<<<dim3(2048, 2), 256, 0, stream>>>(XC, edges, gu, xyz, Wk, Wv, D2, db2, O);

  // K4: feats2 = feats_t + O @ Wo   (bf16 MFMA, in-place resid on F)
  gemm_mfma<<<dim3(2, 128), 256, 0, stream>>>(O, 256, WtO, F, 256, 256, nullptr, 0, F, 256, nullptr, nullptr, nullptr);

  // K5a: LN2 stats
  k5a_stats<<<4096, 256, 0, stream>>>(F, MRS);

  // K5b: Y1 = relu(LN2(feats2) @ W1 + bf1)   (bf16 MFMA, fused LN on A)
  gemm_mfma<<<dim3(4, 128), 256, 0, stream>>>(F, 256, Wt1, Y1, 512, 256, bf1, 1, nullptr, 0, MRS, g2, be2);

  // K6: feats = feats2 + Y1 @ W2 + bf2   (bf16 MFMA, in-place resid on F)
  gemm_mfma<<<dim3(2, 128), 256, 0, stream>>>(Y1, 512, Wt2, F, 256, 512, bf2, 0, F, 256, nullptr, nullptr, nullptr);

  // K7: transpose to (B, C, N)
  k7_transpose<<<dim3(256, 8, 2), 256, 0, stream>>>(F, out);
}

// Round 12
// 355.951 us; speedup vs baseline: 1.6792x; 1.0657x over previous
//
#include <hip/hip_runtime.h>
#include <math.h>

#define NB 8192
#define CC 256

using bf16x8 = __attribute__((ext_vector_type(8))) short;
using f32x4  = __attribute__((ext_vector_type(4))) float;

__device__ inline ushort f2b(float f) {   // f32 -> bf16 RNE
  union { float f; unsigned u; } v; v.f = f;
  unsigned u = v.u;
  u += 0x7FFF + ((u >> 16) & 1);
  return (ushort)(u >> 16);
}
__device__ inline float b2f(ushort h) {
  union { unsigned u; float f; } v; v.u = ((unsigned)h) << 16; return v.f;
}
__device__ inline float u2f(unsigned u) {
  union { unsigned u; float f; } v; v.u = u; return v.f;
}

// ---------------- K0: pack weights bf16 into d_out scratch ----------------
// WtKVQ[768][256]=[Wk_top|Wv_top|Wq]^T ; WtO[256][256]=Wo^T ; Wt1[512][256]=W1^T ;
// Wt2[256][512]=W2^T ; D1hi/D1lo[128][256]=split-bf16 D1^T (hi+lo ~ f32 precision).
__global__ __launch_bounds__(256) void wpackT(const float* __restrict__ Wk, const float* __restrict__ Wv,
                                              const float* __restrict__ Wq, const float* __restrict__ Wo,
                                              const float* __restrict__ W1, const float* __restrict__ W2,
                                              const float* __restrict__ D1,
                                              ushort* __restrict__ WtKVQ, ushort* __restrict__ WtO,
                                              ushort* __restrict__ Wt1, ushort* __restrict__ Wt2,
                                              ushort* __restrict__ D1hi, ushort* __restrict__ D1lo) {
  int i = blockIdx.x * 256 + threadIdx.x;
  if (i < 196608) {
    int n = i >> 8, k = i & 255;
    float v = (n < 256) ? Wk[(size_t)k * 256 + n]
            : (n < 512) ? Wv[(size_t)k * 256 + (n - 256)]
                        : Wq[(size_t)k * 256 + (n - 512)];
    WtKVQ[(size_t)n * 256 + k] = f2b(v);
  } else if (i < 262144) {
    int j = i - 196608; int n = j >> 8, k = j & 255;
    WtO[(size_t)n * 256 + k] = f2b(Wo[(size_t)k * 256 + n]);
  } else if (i < 393216) {
    int j = i - 262144; int n = j >> 8, k = j & 255;
    Wt1[(size_t)n * 256 + k] = f2b(W1[(size_t)k * 512 + n]);
  } else if (i < 524288) {
    int j = i - 393216; int n = j >> 9, k = j & 511;
    Wt2[(size_t)n * 512 + k] = f2b(W2[(size_t)k * 256 + n]);
  } else if (i < 557056) {
    int j = i - 524288; int n = j >> 8, k = j & 255;   // n 0..127
    D1hi[(size_t)n * 256 + k] = f2b(D1[(size_t)k * 128 + n]);
  } else {
    int j = i - 557056; int n = j >> 8, k = j & 255;
    float v = D1[(size_t)k * 128 + n];
    ushort hi = f2b(v);
    D1lo[(size_t)n * 256 + k] = f2b(v - b2f(hi));
  }
}

// ---------------- K1: transpose (B,C,N)->(B,N,C) + LayerNorm1 ----------------
__global__ __launch_bounds__(256) void k1_ln1(const float* __restrict__ features,
                                              const float* __restrict__ g1,
                                              const float* __restrict__ be1,
                                              float* __restrict__ X,
                                              float* __restrict__ F) {
  __shared__ float tile[256][36];
  int b = blockIdx.y;
  int n0 = blockIdx.x * 32;
  int t = threadIdx.x;
  int tn = t & 31, ch = t >> 5;
  for (int cb = 0; cb < 32; ++cb) {
    int c = cb * 8 + ch;
    tile[c][tn] = features[((size_t)b * 256 + c) * NB + n0 + tn];
  }
  __syncthreads();
  int tok = t >> 3, sub = t & 7;
  float s = 0.f, ss = 0.f;
  #pragma unroll
  for (int k = 0; k < 32; ++k) {
    float v = tile[sub + 8 * k][tok];
    s += v; ss += v * v;
  }
  #pragma unroll
  for (int m = 1; m < 8; m <<= 1) { s += __shfl_xor(s, m); ss += __shfl_xor(ss, m); }
  float mean = s * (1.f / 256.f);
  float var  = ss * (1.f / 256.f) - mean * mean;
  float rstd = rsqrtf(var + 1e-6f);
  size_t row = ((size_t)b * NB + n0 + tok) * 256;
  for (int k = 0; k < 32; ++k) {
    int c = sub + 8 * k;
    float v = tile[c][tok];
    F[row + c] = v;
    X[row + c] = (v - mean) * rstd * g1[c] + be1[c];
  }
}

// ---------------- gemm_mfma_x2: split-bf16 3-MFMA GEMM (~f32 accurate), N=128 ----------------
// XD = X @ D1 + db1 via (Ahi+Alo)@(Bhi+Blo) ~= AhiBhi + AhiBlo + AloBhi (err ~2^-17).
__global__ __launch_bounds__(256) void gemm_mfma_x2(
    const float* __restrict__ A, int lda,
    const ushort* __restrict__ Bhi, const ushort* __restrict__ Blo,
    float* __restrict__ Cc, int ldc, int K,
    const float* __restrict__ bias)
{
  __shared__ __align__(16) ushort Ah[128 * 32], Al[128 * 32], Bh[128 * 32], Bl[128 * 32];
  int t = threadIdx.x;
  int m0 = blockIdx.y * 128;
  int wv = t >> 6, lane = t & 63;
  int wm = wv >> 1, wn = wv & 1;
  int lr = lane & 15, kg = lane >> 4;
  f32x4 acc[4][4];
  #pragma unroll
  for (int i = 0; i < 4; ++i)
    #pragma unroll
    for (int j = 0; j < 4; ++j) acc[i][j] = (f32x4)0.0f;

  for (int k0 = 0; k0 < K; k0 += 32) {
    #pragma unroll
    for (int p = 0; p < 2; ++p) {
      int c = t + p * 256;
      int m = c >> 2, kq = c & 3;
      const float* src = &A[(size_t)(m0 + m) * lda + k0 + kq * 8];
      float v[8];
      *(float4*)&v[0] = *(const float4*)src;
      *(float4*)&v[4] = *(const float4*)(src + 4);
      ushort hi[8], lo[8];
      #pragma unroll
      for (int j = 0; j < 8; ++j) {
        hi[j] = f2b(v[j]);
        lo[j] = f2b(v[j] - b2f(hi[j]));
      }
      int off = m * 32 + (kq ^ ((m >> 1) & 3)) * 8;
      *(uint4*)&Ah[off] = *(uint4*)hi;
      *(uint4*)&Al[off] = *(uint4*)lo;
    }
    #pragma unroll
    for (int p = 0; p < 2; ++p) {
      int c = t + p * 256;
      int n = c >> 2, kq = c & 3;
      int off = n * 32 + (kq ^ ((n >> 1) & 3)) * 8;
      *(uint4*)&Bh[off] = *(const uint4*)&Bhi[(size_t)n * K + k0 + kq * 8];
      *(uint4*)&Bl[off] = *(const uint4*)&Blo[(size_t)n * K + k0 + kq * 8];
    }
    __syncthreads();
    bf16x8 ahi[4], alo[4], bhi[4], blo[4];
    #pragma unroll
    for (int mi = 0; mi < 4; ++mi) {
      int m = wm * 64 + mi * 16 + lr;
      int off = m * 32 + (kg ^ ((m >> 1) & 3)) * 8;
      ahi[mi] = *(const bf16x8*)&Ah[off];
      alo[mi] = *(const bf16x8*)&Al[off];
    }
    #pragma unroll
    for (int ni = 0; ni < 4; ++ni) {
      int n = wn * 64 + ni * 16 + lr;
      int off = n * 32 + (kg ^ ((n >> 1) & 3)) * 8;
      bhi[ni] = *(const bf16x8*)&Bh[off];
      blo[ni] = *(const bf16x8*)&Bl[off];
    }
    #pragma unroll
    for (int mi = 0; mi < 4; ++mi)
      #pragma unroll
      for (int ni = 0; ni < 4; ++ni) {
        acc[mi][ni] = __builtin_amdgcn_mfma_f32_16x16x32_bf16(ahi[mi], bhi[ni], acc[mi][ni], 0, 0, 0);
        acc[mi][ni] = __builtin_amdgcn_mfma_f32_16x16x32_bf16(ahi[mi], blo[ni], acc[mi][ni], 0, 0, 0);
        acc[mi][ni] = __builtin_amdgcn_mfma_f32_16x16x32_bf16(alo[mi], bhi[ni], acc[mi][ni], 0, 0, 0);
      }
    __syncthreads();
  }
  #pragma unroll
  for (int ni = 0; ni < 4; ++ni) {
    int col = wn * 64 + ni * 16 + lr;
    float bv = bias[col];
    #pragma unroll
    for (int mi = 0; mi < 4; ++mi)
      #pragma unroll
      for (int r = 0; r < 4; ++r) {
        int row = m0 + wm * 64 + mi * 16 + kg * 4 + r;
        Cc[(size_t)row * ldc + col] = acc[mi][ni][r] + bv;
      }
  }
}

// ---------------- gemm_mfma: bf16 MFMA GEMM, f32 out, 128x128 tile ----------------
__global__ __launch_bounds__(256) void gemm_mfma(
    const float* __restrict__ A, int lda,
    const ushort* __restrict__ Bt,
    float* __restrict__ Cc, int ldc,
    int K,
    const float* __restrict__ bias, int relu,
    const float* __restrict__ resid, int ldr,
    const float* __restrict__ mrs, const float* __restrict__ lg, const float* __restrict__ lb)
{
  __shared__ __align__(16) ushort As[128 * 32];
  __shared__ __align__(16) ushort Bs[128 * 32];
  int t = threadIdx.x;
  int m0 = blockIdx.y * 128, n0 = blockIdx.x * 128;
  int wv = t >> 6, lane = t & 63;
  int wm = wv >> 1, wn = wv & 1;
  int lr = lane & 15, kg = lane >> 4;
  f32x4 acc[4][4];
  #pragma unroll
  for (int i = 0; i < 4; ++i)
    #pragma unroll
    for (int j = 0; j < 4; ++j) acc[i][j] = (f32x4)0.0f;

  for (int k0 = 0; k0 < K; k0 += 32) {
    #pragma unroll
    for (int p = 0; p < 2; ++p) {
      int c = t + p * 256;
      int m = c >> 2, kq = c & 3;
      const float* src = &A[(size_t)(m0 + m) * lda + k0 + kq * 8];
      float v[8];
      *(float4*)&v[0] = *(const float4*)src;
      *(float4*)&v[4] = *(const float4*)(src + 4);
      if (mrs) {
        float mean = mrs[(m0 + m) * 2], rstd = mrs[(m0 + m) * 2 + 1];
        #pragma unroll
        for (int j = 0; j < 8; ++j) {
          int kk = k0 + kq * 8 + j;
          v[j] = (v[j] - mean) * rstd * lg[kk] + lb[kk];
        }
      }
      ushort o[8];
      #pragma unroll
      for (int j = 0; j < 8; ++j) o[j] = f2b(v[j]);
      *(uint4*)&As[m * 32 + (kq ^ ((m >> 1) & 3)) * 8] = *(uint4*)o;
    }
    #pragma unroll
    for (int p = 0; p < 2; ++p) {
      int c = t + p * 256;
      int n = c >> 2, kq = c & 3;
      uint4 w = *(const uint4*)&Bt[(size_t)(n0 + n) * K + k0 + kq * 8];
      *(uint4*)&Bs[n * 32 + (kq ^ ((n >> 1) & 3)) * 8] = w;
    }
    __syncthreads();
    bf16x8 af[4], bfr[4];
    #pragma unroll
    for (int mi = 0; mi < 4; ++mi) {
      int m = wm * 64 + mi * 16 + lr;
      af[mi] = *(const bf16x8*)&As[m * 32 + (kg ^ ((m >> 1) & 3)) * 8];
    }
    #pragma unroll
    for (int ni = 0; ni < 4; ++ni) {
      int n = wn * 64 + ni * 16 + lr;
      bfr[ni] = *(const bf16x8*)&Bs[n * 32 + (kg ^ ((n >> 1) & 3)) * 8];
    }
    #pragma unroll
    for (int mi = 0; mi < 4; ++mi)
      #pragma unroll
      for (int ni = 0; ni < 4; ++ni)
        acc[mi][ni] = __builtin_amdgcn_mfma_f32_16x16x32_bf16(af[mi], bfr[ni], acc[mi][ni], 0, 0, 0);
    __syncthreads();
  }
  #pragma unroll
  for (int ni = 0; ni < 4; ++ni) {
    int col = n0 + wn * 64 + ni * 16 + lr;
    float bv = bias ? bias[col] : 0.f;
    #pragma unroll
    for (int mi = 0; mi < 4; ++mi) {
      #pragma unroll
      for (int r = 0; r < 4; ++r) {
        int row = m0 + wm * 64 + mi * 16 + kg * 4 + r;
        float v = acc[mi][ni][r] + bv;
        if (relu) v = fmaxf(v, 0.f);
        if (resid) v += resid[(size_t)row * ldr + col];
        Cc[(size_t)row * ldc + col] = v;
      }
    }
  }
}

// ---------------- gemm_mfma_b16o: same, bf16 output (for XKV) ----------------
__global__ __launch_bounds__(256) void gemm_mfma_b16o(
    const float* __restrict__ A, int lda,
    const ushort* __restrict__ Bt,
    ushort* __restrict__ Cc, int ldc, int K)
{
  __shared__ __align__(16) ushort As[128 * 32];
  __shared__ __align__(16) ushort Bs[128 * 32];
  int t = threadIdx.x;
  int m0 = blockIdx.y * 128, n0 = blockIdx.x * 128;
  int wv = t >> 6, lane = t & 63;
  int wm = wv >> 1, wn = wv & 1;
  int lr = lane & 15, kg = lane >> 4;
  f32x4 acc[4][4];
  #pragma unroll
  for (int i = 0; i < 4; ++i)
    #pragma unroll
    for (int j = 0; j < 4; ++j) acc[i][j] = (f32x4)0.0f;

  for (int k0 = 0; k0 < K; k0 += 32) {
    #pragma unroll
    for (int p = 0; p < 2; ++p) {
      int c = t + p * 256;
      int m = c >> 2, kq = c & 3;
      const float* src = &A[(size_t)(m0 + m) * lda + k0 + kq * 8];
      float v[8];
      *(float4*)&v[0] = *(const float4*)src;
      *(float4*)&v[4] = *(const float4*)(src + 4);
      ushort o[8];
      #pragma unroll
      for (int j = 0; j < 8; ++j) o[j] = f2b(v[j]);
      *(uint4*)&As[m * 32 + (kq ^ ((m >> 1) & 3)) * 8] = *(uint4*)o;
    }
    #pragma unroll
    for (int p = 0; p < 2; ++p) {
      int c = t + p * 256;
      int n = c >> 2, kq = c & 3;
      uint4 w = *(const uint4*)&Bt[(size_t)(n0 + n) * K + k0 + kq * 8];
      *(uint4*)&Bs[n * 32 + (kq ^ ((n >> 1) & 3)) * 8] = w;
    }
    __syncthreads();
    bf16x8 af[4], bfr[4];
    #pragma unroll
    for (int mi = 0; mi < 4; ++mi) {
      int m = wm * 64 + mi * 16 + lr;
      af[mi] = *(const bf16x8*)&As[m * 32 + (kg ^ ((m >> 1) & 3)) * 8];
    }
    #pragma unroll
    for (int ni = 0; ni < 4; ++ni) {
      int n = wn * 64 + ni * 16 + lr;
      bfr[ni] = *(const bf16x8*)&Bs[n * 32 + (kg ^ ((n >> 1) & 3)) * 8];
    }
    #pragma unroll
    for (int mi = 0; mi < 4; ++mi)
      #pragma unroll
      for (int ni = 0; ni < 4; ++ni)
        acc[mi][ni] = __builtin_amdgcn_mfma_f32_16x16x32_bf16(af[mi], bfr[ni], acc[mi][ni], 0, 0, 0);
    __syncthreads();
  }
  #pragma unroll
  for (int ni = 0; ni < 4; ++ni) {
    int col = n0 + wn * 64 + ni * 16 + lr;
    #pragma unroll
    for (int mi = 0; mi < 4; ++mi)
      #pragma unroll
      for (int r = 0; r < 4; ++r) {
        int row = m0 + wm * 64 + mi * 16 + kg * 4 + r;
        Cc[(size_t)row * ldc + col] = f2b(acc[mi][ni][r]);
      }
  }
}

// ---------------- K3: wave-per-token gumbel-softmax + attention (bf16 KV gathers) ----------------
// XD f32 [tok][128] (db1 folded); XKV bf16 [tok][xk 256 | xv 256]; XQ f32 [tok][256].
__global__ __launch_bounds__(256) void k3_wave(
    const float* __restrict__ XD,
    const ushort* __restrict__ XKV,
    const float* __restrict__ XQ,
    const int* __restrict__ edges,
    const float* __restrict__ gu,
    const float* __restrict__ xyz,
    const float* __restrict__ Wk, const float* __restrict__ Wv,
    const float* __restrict__ D2, const float* __restrict__ db2,
    float* __restrict__ O)
{
  __shared__ float d2s[1024];
  int t = threadIdx.x;
  for (int i = t; i < 1024; i += 256) {
    int f = i >> 3, d = i & 7;
    d2s[f * 8 + (d ^ (f >> 5))] = D2[i];
  }
  __syncthreads();

  int wv = t >> 6, lane = t & 63;
  int b = blockIdx.y;
  int n = blockIdx.x * 4 + wv;
  size_t bn = (size_t)b * NB + n;
  int e = lane >> 2, fq = lane & 3;

  int idx = edges[(bn * 16 + e) * 2];

  // --- h-phase: h[e][d] = db2[d] + sum_f relu(xD[idx[e]][f]) * D2[f][d]
  float acc[8] = {0.f, 0.f, 0.f, 0.f, 0.f, 0.f, 0.f, 0.f};
  const float4* xd4 = (const float4*)(XD + ((size_t)b * NB + idx) * 128 + fq * 32);
  #pragma unroll
  for (int i = 0; i < 8; ++i) {
    float4 xd = xd4[i];
    float xv[4] = {fmaxf(xd.x, 0.f), fmaxf(xd.y, 0.f), fmaxf(xd.z, 0.f), fmaxf(xd.w, 0.f)};
    #pragma unroll
    for (int j = 0; j < 4; ++j) {
      int f = fq * 32 + i * 4 + j;
      #pragma unroll
      for (int d = 0; d < 8; ++d)
        acc[d] += xv[j] * d2s[f * 8 + (d ^ fq)];
    }
  }
  #pragma unroll
  for (int d = 0; d < 8; ++d) {
    acc[d] += __shfl_xor(acc[d], 1);
    acc[d] += __shfl_xor(acc[d], 2);
    acc[d] += db2[d];
  }

  // --- gumbel softmax over e (masks 4..32)
  float w[8];
  #pragma unroll
  for (int d = 0; d < 8; ++d) {
    float u = gu[(bn * 8 + d) * 16 + e];
    float gn = -logf(-logf(u));
    float val = (acc[d] + gn) * 10.0f;   // 1/TAU
    float mx = val;
    mx = fmaxf(mx, __shfl_xor(mx, 4));
    mx = fmaxf(mx, __shfl_xor(mx, 8));
    mx = fmaxf(mx, __shfl_xor(mx, 16));
    mx = fmaxf(mx, __shfl_xor(mx, 32));
    float ex = expf(val - mx);
    float sm = ex;
    sm += __shfl_xor(sm, 4);
    sm += __shfl_xor(sm, 8);
    sm += __shfl_xor(sm, 16);
    sm += __shfl_xor(sm, 32);
    w[d] = ex / sm;
  }

  // --- weighted xyz
  float xg = (fq < 3) ? xyz[((size_t)b * NB + idx) * 3 + fq] : 0.f;
  float xo = (fq < 3) ? xyz[bn * 3 + fq] : 0.f;
  float scw[8];
  #pragma unroll
  for (int d = 0; d < 8; ++d) {
    float s = w[d] * xg;
    s += __shfl_xor(s, 4);
    s += __shfl_xor(s, 8);
    s += __shfl_xor(s, 16);
    s += __shfl_xor(s, 32);
    scw[d] = s - xo;   // sum(w)==1 makes the -xyz fold exact
  }

  // --- k,v combine; lane owns channels c = lane*4..+3 (bf16 gathers, 8B each)
  float4 kk[8], vv[8];
  #pragma unroll
  for (int d = 0; d < 8; ++d) {
    kk[d].x = kk[d].y = kk[d].z = kk[d].w = 0.f;
    vv[d].x = vv[d].y = vv[d].z = vv[d].w = 0.f;
  }
  #pragma unroll
  for (int j = 0; j < 3; ++j) {
    float4 wkb = *(const float4*)&Wk[(size_t)(256 + j) * 256 + lane * 4];
    float4 wvb = *(const float4*)&Wv[(size_t)(256 + j) * 256 + lane * 4];
    #pragma unroll
    for (int d = 0; d < 8; ++d) {
      float sc = __shfl(scw[d], (lane & ~3) | j);
      kk[d].x += sc * wkb.x; kk[d].y += sc * wkb.y; kk[d].z += sc * wkb.z; kk[d].w += sc * wkb.w;
      vv[d].x += sc * wvb.x; vv[d].y += sc * wvb.y; vv[d].z += sc * wvb.z; vv[d].w += sc * wvb.w;
    }
  }
  #pragma unroll 8
  for (int ee = 0; ee < 16; ++ee) {
    int eidx = __shfl(idx, ee * 4);
    const ushort* rE = XKV + ((size_t)b * NB + eidx) * 512;
    uint2 ku = *(const uint2*)(rE + lane * 4);
    uint2 vu = *(const uint2*)(rE + 256 + lane * 4);
    float xk0 = u2f(ku.x << 16), xk1 = u2f(ku.x & 0xFFFF0000u);
    float xk2 = u2f(ku.y << 16), xk3 = u2f(ku.y & 0xFFFF0000u);
    float xv0 = u2f(vu.x << 16), xv1 = u2f(vu.x & 0xFFFF0000u);
    float xv2 = u2f(vu.y << 16), xv3 = u2f(vu.y & 0xFFFF0000u);
    #pragma unroll
    for (int d = 0; d < 8; ++d) {
      float wd = __shfl(w[d], ee * 4);
      kk[d].x += wd * xk0; kk[d].y += wd * xk1; kk[d].z += wd * xk2; kk[d].w += wd * xk3;
      vv[d].x += wd * xv0; vv[d].y += wd * xv1; vv[d].z += wd * xv2; vv[d].w += wd * xv3;
    }
  }

  // --- attention: per-HEAD reduce (masks 1,2,4)
  float4 q = ((const float4*)(XQ + bn * 256))[lane];
  float sim[8];
  #pragma unroll
  for (int d = 0; d < 8; ++d) {
    float p = q.x * kk[d].x + q.y * kk[d].y + q.z * kk[d].z + q.w * kk[d].w;
    p += __shfl_xor(p, 1);
    p += __shfl_xor(p, 2);
    p += __shfl_xor(p, 4);
    sim[d] = p * 0.17677669529663687f;   // 1/sqrt(32)
  }
  float mx = sim[0];
  #pragma unroll
  for (int d = 1; d < 8; ++d) mx = fmaxf(mx, sim[d]);
  float e8[8], sume = 0.f;
  #pragma unroll
  for (int d = 0; d < 8; ++d) { e8[d] = expf(sim[d] - mx); sume += e8[d]; }
  float inv = 1.f / sume;
  float4 oc; oc.x = oc.y = oc.z = oc.w = 0.f;
  #pragma unroll
  for (int d = 0; d < 8; ++d) {
    float sm = e8[d] * inv;
    oc.x += vv[d].x * sm; oc.y += vv[d].y * sm; oc.z += vv[d].z * sm; oc.w += vv[d].w * sm;
  }
  ((float4*)(O + bn * 256))[lane] = oc;
}

// ---------------- K5a: per-row mean/rstd for LN2 ----------------
__global__ __launch_bounds__(256) void k5a_stats(const float* __restrict__ F, float* __restrict__ MRS) {
  int wave = threadIdx.x >> 6, lane = threadIdx.x & 63;
  size_t row = (size_t)blockIdx.x * 4 + wave;
  float4 v4 = *(const float4*)&F[row * 256 + lane * 4];
  float s = v4.x + v4.y + v4.z + v4.w;
  float ss = v4.x * v4.x + v4.y * v4.y + v4.z * v4.z + v4.w * v4.w;
  #pragma unroll
  for (int m = 1; m < 64; m <<= 1) { s += __shfl_xor(s, m); ss += __shfl_xor(ss, m); }
  if (lane == 0) {
    float mean = s * (1.f / 256.f);
    float var = ss * (1.f / 256.f) - mean * mean;
    MRS[row * 2] = mean;
    MRS[row * 2 + 1] = rsqrtf(var + 1e-6f);
  }
}

// ---------------- K7: transpose (B,N,C) -> (B,C,N) ----------------
__global__ __launch_bounds__(256) void k7_transpose(const float* __restrict__ F, float* __restrict__ out) {
  __shared__ float tile[32][33];
  int b = blockIdx.z;
  int c0 = blockIdx.y * 32;
  int n0 = blockIdx.x * 32;
  int t = threadIdx.x;
  int nl = t >> 5, cl = t & 31;
  #pragma unroll
  for (int i = 0; i < 4; ++i) {
    int nn = nl + i * 8;
    tile[nn][cl] = F[((size_t)b * NB + n0 + nn) * 256 + c0 + cl];
  }
  __syncthreads();
  int cl2 = t >> 5, nl2 = t & 31;
  #pragma unroll
  for (int i = 0; i < 4; ++i) {
    int cc = cl2 + i * 8;
    out[((size_t)b * 256 + c0 + cc) * NB + n0 + nl2] = tile[nl2][cc];
  }
}

extern "C" void kernel_launch(void* const* d_in, const int* in_sizes, int n_in,
                              void* d_out, int out_size, void* d_ws, size_t ws_size,
                              hipStream_t stream) {
  const float* xyz      = (const float*)d_in[0];
  const float* features = (const float*)d_in[1];
  const int*   edges    = (const int*)d_in[2];
  const float* gu       = (const float*)d_in[3];
  const float* g1       = (const float*)d_in[4];
  const float* be1      = (const float*)d_in[5];
  const float* Wq       = (const float*)d_in[6];
  const float* Wk       = (const float*)d_in[7];
  const float* Wv       = (const float*)d_in[8];
  const float* Wo       = (const float*)d_in[9];
  const float* g2       = (const float*)d_in[10];
  const float* be2      = (const float*)d_in[11];
  const float* W1       = (const float*)d_in[12];
  const float* bf1      = (const float*)d_in[13];
  const float* W2       = (const float*)d_in[14];
  const float* bf2      = (const float*)d_in[15];
  const float* D1       = (const float*)d_in[16];
  const float* db1      = (const float*)d_in[17];
  const float* D2       = (const float*)d_in[18];
  const float* db2      = (const float*)d_in[19];
  float* out = (float*)d_out;
  float* ws  = (float*)d_ws;

  // ws layout (75.5 MB peak):
  float*  X   = ws;                         // 16384x256 f32 LN1; dead after K2b-q; reused as O
  float*  F   = ws + 4194304;               // 16384x256 feats (in-place chain)
  float*  XD  = ws + 8388608;               // 16384x128 f32 (dead after K3)
  ushort* XKV = (ushort*)(ws + 10485760);   // 16384x512 bf16 (dead after K3)
  float*  XQ  = ws + 14680064;              // 16384x256 f32 (dead after K3)
  float*  O   = X;
  float*  Y1  = ws + 8388608;               // 16384x512 f32 (overwrites XD/XKV after K3)

  // d_out scratch (dead before K7 writes it): bf16 weight packs + MRS
  ushort* WtKVQ = (ushort*)out;             // 768x256
  ushort* WtO   = WtKVQ + 196608;           // 256x256
  ushort* Wt1   = WtO + 65536;              // 512x256
  ushort* Wt2   = Wt1 + 131072;             // 256x512
  ushort* D1hi  = Wt2 + 131072;             // 128x256
  ushort* D1lo  = D1hi + 32768;             // 128x256  (ends at 589824 ushorts)
  float*  MRS   = out + 294912;             // 16384x2

  // K0: pack weights
  wpackT<<<2304, 256, 0, stream>>>(Wk, Wv, Wq, Wo, W1, W2, D1, WtKVQ, WtO, Wt1, Wt2, D1hi, D1lo);

  // K1: transpose + LN1
  k1_ln1<<<dim3(256, 2), 256, 0, stream>>>(features, g1, be1, X, F);

  // K2a: XD = X @ D1 + db1  (split-bf16 3-MFMA ~ f32 accuracy for the x10 gumbel path)
  gemm_mfma_x2<<<dim3(1, 128), 256, 0, stream>>>(X, 256, D1hi, D1lo, XD, 128, 256, db1);

  // K2b-kv: XKV = bf16(X @ [Wk_top|Wv_top])
  gemm_mfma_b16o<<<dim3(4, 128), 256, 0, stream>>>(X, 256, WtKVQ, XKV, 512, 256);

  // K2b-q: XQ = X @ Wq (f32 out)
  gemm_mfma<<<dim3(2, 128), 256, 0, stream>>>(X, 256, WtKVQ + 512 * 256, XQ, 256, 256,
                                              nullptr, 0, nullptr, 0, nullptr, nullptr, nullptr);

  // K3: gumbel-softmax + attention -> O
  k3_wave<<<dim3(2048, 2), 256, 0, stream>>>(XD, XKV, XQ, edges, gu, xyz, Wk, Wv, D2, db2, O);

  // K4: feats2 = feats_t + O @ Wo
  gemm_mfma<<<dim3(2, 128), 256, 0, stream>>>(O, 256, WtO, F, 256, 256,
                                              nullptr, 0, F, 256, nullptr, nullptr, nullptr);

  // K5a: LN2 stats
  k5a_stats<<<4096, 256, 0, stream>>>(F, MRS);

  // K5b: Y1 = relu(LN2(feats2) @ W1 + bf1)
  gemm_mfma<<<dim3(4, 128), 256, 0, stream>>>(F, 256, Wt1, Y1, 512, 256,
                                              bf1, 1, nullptr, 0, MRS, g2, be2);

  // K6: feats = feats2 + Y1 @ W2 + bf2
  gemm_mfma<<<dim3(2, 128), 256, 0, stream>>>(Y1, 512, Wt2, F, 256, 512,
                                              bf2, 0, F, 256, nullptr, nullptr, nullptr);

  // K7: transpose to (B, C, N)
  k7_transpose<<<dim3(256, 8, 2), 256, 0, stream>>>(F, out);
}

// Round 13
// 355.155 us; speedup vs baseline: 1.6830x; 1.0022x over previous
//
#include <hip/hip_runtime.h>
#include <math.h>

#define NB 8192
#define CC 256

using bf16x8 = __attribute__((ext_vector_type(8))) short;
using f32x4  = __attribute__((ext_vector_type(4))) float;

__device__ inline ushort f2b(float f) {   // f32 -> bf16 RNE
  union { float f; unsigned u; } v; v.f = f;
  unsigned u = v.u;
  u += 0x7FFF + ((u >> 16) & 1);
  return (ushort)(u >> 16);
}
__device__ inline float b2f(ushort h) {
  union { unsigned u; float f; } v; v.u = ((unsigned)h) << 16; return v.f;
}
__device__ inline float u2f(unsigned u) {
  union { unsigned u; float f; } v; v.u = u; return v.f;
}

// ---------------- K0: pack weights bf16 into d_out scratch ----------------
__global__ __launch_bounds__(256) void wpackT(const float* __restrict__ Wk, const float* __restrict__ Wv,
                                              const float* __restrict__ Wq, const float* __restrict__ Wo,
                                              const float* __restrict__ W1, const float* __restrict__ W2,
                                              const float* __restrict__ D1,
                                              ushort* __restrict__ WtKVQ, ushort* __restrict__ WtO,
                                              ushort* __restrict__ Wt1, ushort* __restrict__ Wt2,
                                              ushort* __restrict__ D1hi, ushort* __restrict__ D1lo) {
  int i = blockIdx.x * 256 + threadIdx.x;
  if (i < 196608) {
    int n = i >> 8, k = i & 255;
    float v = (n < 256) ? Wk[(size_t)k * 256 + n]
            : (n < 512) ? Wv[(size_t)k * 256 + (n - 256)]
                        : Wq[(size_t)k * 256 + (n - 512)];
    WtKVQ[(size_t)n * 256 + k] = f2b(v);
  } else if (i < 262144) {
    int j = i - 196608; int n = j >> 8, k = j & 255;
    WtO[(size_t)n * 256 + k] = f2b(Wo[(size_t)k * 256 + n]);
  } else if (i < 393216) {
    int j = i - 262144; int n = j >> 8, k = j & 255;
    Wt1[(size_t)n * 256 + k] = f2b(W1[(size_t)k * 512 + n]);
  } else if (i < 524288) {
    int j = i - 393216; int n = j >> 9, k = j & 511;
    Wt2[(size_t)n * 512 + k] = f2b(W2[(size_t)k * 256 + n]);
  } else if (i < 557056) {
    int j = i - 524288; int n = j >> 8, k = j & 255;   // n 0..127
    D1hi[(size_t)n * 256 + k] = f2b(D1[(size_t)k * 128 + n]);
  } else {
    int j = i - 557056; int n = j >> 8, k = j & 255;
    float v = D1[(size_t)k * 128 + n];
    ushort hi = f2b(v);
    D1lo[(size_t)n * 256 + k] = f2b(v - b2f(hi));
  }
}

// ---------------- K1: transpose (B,C,N)->(B,N,C) + LayerNorm1 ----------------
__global__ __launch_bounds__(256) void k1_ln1(const float* __restrict__ features,
                                              const float* __restrict__ g1,
                                              const float* __restrict__ be1,
                                              float* __restrict__ X,
                                              float* __restrict__ F) {
  __shared__ float tile[256][36];
  int b = blockIdx.y;
  int n0 = blockIdx.x * 32;
  int t = threadIdx.x;
  int tn = t & 31, ch = t >> 5;
  for (int cb = 0; cb < 32; ++cb) {
    int c = cb * 8 + ch;
    tile[c][tn] = features[((size_t)b * 256 + c) * NB + n0 + tn];
  }
  __syncthreads();
  int tok = t >> 3, sub = t & 7;
  float s = 0.f, ss = 0.f;
  #pragma unroll
  for (int k = 0; k < 32; ++k) {
    float v = tile[sub + 8 * k][tok];
    s += v; ss += v * v;
  }
  #pragma unroll
  for (int m = 1; m < 8; m <<= 1) { s += __shfl_xor(s, m); ss += __shfl_xor(ss, m); }
  float mean = s * (1.f / 256.f);
  float var  = ss * (1.f / 256.f) - mean * mean;
  float rstd = rsqrtf(var + 1e-6f);
  size_t row = ((size_t)b * NB + n0 + tok) * 256;
  for (int k = 0; k < 32; ++k) {
    int c = sub + 8 * k;
    float v = tile[c][tok];
    F[row + c] = v;
    X[row + c] = (v - mean) * rstd * g1[c] + be1[c];
  }
}

// ---------------- K2 fused: XD (split-bf16 x2) | XKV (bf16 out) | XQ (f32 out) ----------------
// All three GEMMs share A = X [16384][256]; dispatched by blockIdx.x:
//   bx==0   : XD = X @ D1 + db1 (3-MFMA split-bf16, ~f32 accurate for the x10 gumbel path)
//   bx 1..4 : XKV = bf16(X @ [Wk_top|Wv_top]), n0=(bx-1)*128, ldc 512
//   bx 5..6 : XQ = X @ Wq (f32), n0=(bx-5)*128, ldc 256
__global__ __launch_bounds__(256) void k2_fused(
    const float* __restrict__ X,
    const ushort* __restrict__ D1hi, const ushort* __restrict__ D1lo,
    const float* __restrict__ db1, float* __restrict__ XD,
    const ushort* __restrict__ WtKVQ, ushort* __restrict__ XKV,
    float* __restrict__ XQ)
{
  __shared__ __align__(16) ushort S[4 * 128 * 32];   // 32 KB
  int t = threadIdx.x;
  int m0 = blockIdx.y * 128;
  int wv = t >> 6, lane = t & 63;
  int wm = wv >> 1, wn = wv & 1;
  int lr = lane & 15, kg = lane >> 4;
  const int K = 256, lda = 256;
  int bx = blockIdx.x;

  f32x4 acc[4][4];
  #pragma unroll
  for (int i = 0; i < 4; ++i)
    #pragma unroll
    for (int j = 0; j < 4; ++j) acc[i][j] = (f32x4)0.0f;

  if (bx == 0) {
    ushort* Ah = S;            ushort* Al = S + 4096;
    ushort* Bh = S + 8192;     ushort* Bl = S + 12288;
    for (int k0 = 0; k0 < K; k0 += 32) {
      #pragma unroll
      for (int p = 0; p < 2; ++p) {
        int c = t + p * 256;
        int m = c >> 2, kq = c & 3;
        const float* src = &X[(size_t)(m0 + m) * lda + k0 + kq * 8];
        float v[8];
        *(float4*)&v[0] = *(const float4*)src;
        *(float4*)&v[4] = *(const float4*)(src + 4);
        ushort hi[8], lo[8];
        #pragma unroll
        for (int j = 0; j < 8; ++j) {
          hi[j] = f2b(v[j]);
          lo[j] = f2b(v[j] - b2f(hi[j]));
        }
        int off = m * 32 + (kq ^ ((m >> 1) & 3)) * 8;
        *(uint4*)&Ah[off] = *(uint4*)hi;
        *(uint4*)&Al[off] = *(uint4*)lo;
      }
      #pragma unroll
      for (int p = 0; p < 2; ++p) {
        int c = t + p * 256;
        int n = c >> 2, kq = c & 3;
        int off = n * 32 + (kq ^ ((n >> 1) & 3)) * 8;
        *(uint4*)&Bh[off] = *(const uint4*)&D1hi[(size_t)n * K + k0 + kq * 8];
        *(uint4*)&Bl[off] = *(const uint4*)&D1lo[(size_t)n * K + k0 + kq * 8];
      }
      __syncthreads();
      bf16x8 ahi[4], alo[4], bhi[4], blo[4];
      #pragma unroll
      for (int mi = 0; mi < 4; ++mi) {
        int m = wm * 64 + mi * 16 + lr;
        int off = m * 32 + (kg ^ ((m >> 1) & 3)) * 8;
        ahi[mi] = *(const bf16x8*)&Ah[off];
        alo[mi] = *(const bf16x8*)&Al[off];
      }
      #pragma unroll
      for (int ni = 0; ni < 4; ++ni) {
        int n = wn * 64 + ni * 16 + lr;
        int off = n * 32 + (kg ^ ((n >> 1) & 3)) * 8;
        bhi[ni] = *(const bf16x8*)&Bh[off];
        blo[ni] = *(const bf16x8*)&Bl[off];
      }
      #pragma unroll
      for (int mi = 0; mi < 4; ++mi)
        #pragma unroll
        for (int ni = 0; ni < 4; ++ni) {
          acc[mi][ni] = __builtin_amdgcn_mfma_f32_16x16x32_bf16(ahi[mi], bhi[ni], acc[mi][ni], 0, 0, 0);
          acc[mi][ni] = __builtin_amdgcn_mfma_f32_16x16x32_bf16(ahi[mi], blo[ni], acc[mi][ni], 0, 0, 0);
          acc[mi][ni] = __builtin_amdgcn_mfma_f32_16x16x32_bf16(alo[mi], bhi[ni], acc[mi][ni], 0, 0, 0);
        }
      __syncthreads();
    }
    #pragma unroll
    for (int ni = 0; ni < 4; ++ni) {
      int col = wn * 64 + ni * 16 + lr;
      float bv = db1[col];
      #pragma unroll
      for (int mi = 0; mi < 4; ++mi)
        #pragma unroll
        for (int r = 0; r < 4; ++r) {
          int row = m0 + wm * 64 + mi * 16 + kg * 4 + r;
          XD[(size_t)row * 128 + col] = acc[mi][ni][r] + bv;
        }
    }
  } else {
    ushort* As = S;  ushort* Bs = S + 4096;
    bool isKV = (bx <= 4);
    int n0 = isKV ? (bx - 1) * 128 : (bx - 5) * 128;
    const ushort* Bt = isKV ? WtKVQ : (WtKVQ + 512 * 256);
    for (int k0 = 0; k0 < K; k0 += 32) {
      #pragma unroll
      for (int p = 0; p < 2; ++p) {
        int c = t + p * 256;
        int m = c >> 2, kq = c & 3;
        const float* src = &X[(size_t)(m0 + m) * lda + k0 + kq * 8];
        float v[8];
        *(float4*)&v[0] = *(const float4*)src;
        *(float4*)&v[4] = *(const float4*)(src + 4);
        ushort o[8];
        #pragma unroll
        for (int j = 0; j < 8; ++j) o[j] = f2b(v[j]);
        *(uint4*)&As[m * 32 + (kq ^ ((m >> 1) & 3)) * 8] = *(uint4*)o;
      }
      #pragma unroll
      for (int p = 0; p < 2; ++p) {
        int c = t + p * 256;
        int n = c >> 2, kq = c & 3;
        uint4 w = *(const uint4*)&Bt[(size_t)(n0 + n) * K + k0 + kq * 8];
        *(uint4*)&Bs[n * 32 + (kq ^ ((n >> 1) & 3)) * 8] = w;
      }
      __syncthreads();
      bf16x8 af[4], bfr[4];
      #pragma unroll
      for (int mi = 0; mi < 4; ++mi) {
        int m = wm * 64 + mi * 16 + lr;
        af[mi] = *(const bf16x8*)&As[m * 32 + (kg ^ ((m >> 1) & 3)) * 8];
      }
      #pragma unroll
      for (int ni = 0; ni < 4; ++ni) {
        int n = wn * 64 + ni * 16 + lr;
        bfr[ni] = *(const bf16x8*)&Bs[n * 32 + (kg ^ ((n >> 1) & 3)) * 8];
      }
      #pragma unroll
      for (int mi = 0; mi < 4; ++mi)
        #pragma unroll
        for (int ni = 0; ni < 4; ++ni)
          acc[mi][ni] = __builtin_amdgcn_mfma_f32_16x16x32_bf16(af[mi], bfr[ni], acc[mi][ni], 0, 0, 0);
      __syncthreads();
    }
    if (isKV) {
      #pragma unroll
      for (int ni = 0; ni < 4; ++ni) {
        int col = n0 + wn * 64 + ni * 16 + lr;
        #pragma unroll
        for (int mi = 0; mi < 4; ++mi)
          #pragma unroll
          for (int r = 0; r < 4; ++r) {
            int row = m0 + wm * 64 + mi * 16 + kg * 4 + r;
            XKV[(size_t)row * 512 + col] = f2b(acc[mi][ni][r]);
          }
      }
    } else {
      #pragma unroll
      for (int ni = 0; ni < 4; ++ni) {
        int col = n0 + wn * 64 + ni * 16 + lr;
        #pragma unroll
        for (int mi = 0; mi < 4; ++mi)
          #pragma unroll
          for (int r = 0; r < 4; ++r) {
            int row = m0 + wm * 64 + mi * 16 + kg * 4 + r;
            XQ[(size_t)row * 256 + col] = acc[mi][ni][r];
          }
      }
    }
  }
}

// ---------------- gemm_mfma: bf16 MFMA GEMM, f32 out, 128x128 tile (K4/K5b/K6) ----------------
__global__ __launch_bounds__(256) void gemm_mfma(
    const float* __restrict__ A, int lda,
    const ushort* __restrict__ Bt,
    float* __restrict__ Cc, int ldc,
    int K,
    const float* __restrict__ bias, int relu,
    const float* __restrict__ resid, int ldr,
    const float* __restrict__ mrs, const float* __restrict__ lg, const float* __restrict__ lb)
{
  __shared__ __align__(16) ushort As[128 * 32];
  __shared__ __align__(16) ushort Bs[128 * 32];
  int t = threadIdx.x;
  int m0 = blockIdx.y * 128, n0 = blockIdx.x * 128;
  int wv = t >> 6, lane = t & 63;
  int wm = wv >> 1, wn = wv & 1;
  int lr = lane & 15, kg = lane >> 4;
  f32x4 acc[4][4];
  #pragma unroll
  for (int i = 0; i < 4; ++i)
    #pragma unroll
    for (int j = 0; j < 4; ++j) acc[i][j] = (f32x4)0.0f;

  for (int k0 = 0; k0 < K; k0 += 32) {
    #pragma unroll
    for (int p = 0; p < 2; ++p) {
      int c = t + p * 256;
      int m = c >> 2, kq = c & 3;
      const float* src = &A[(size_t)(m0 + m) * lda + k0 + kq * 8];
      float v[8];
      *(float4*)&v[0] = *(const float4*)src;
      *(float4*)&v[4] = *(const float4*)(src + 4);
      if (mrs) {
        float mean = mrs[(m0 + m) * 2], rstd = mrs[(m0 + m) * 2 + 1];
        #pragma unroll
        for (int j = 0; j < 8; ++j) {
          int kk = k0 + kq * 8 + j;
          v[j] = (v[j] - mean) * rstd * lg[kk] + lb[kk];
        }
      }
      ushort o[8];
      #pragma unroll
      for (int j = 0; j < 8; ++j) o[j] = f2b(v[j]);
      *(uint4*)&As[m * 32 + (kq ^ ((m >> 1) & 3)) * 8] = *(uint4*)o;
    }
    #pragma unroll
    for (int p = 0; p < 2; ++p) {
      int c = t + p * 256;
      int n = c >> 2, kq = c & 3;
      uint4 w = *(const uint4*)&Bt[(size_t)(n0 + n) * K + k0 + kq * 8];
      *(uint4*)&Bs[n * 32 + (kq ^ ((n >> 1) & 3)) * 8] = w;
    }
    __syncthreads();
    bf16x8 af[4], bfr[4];
    #pragma unroll
    for (int mi = 0; mi < 4; ++mi) {
      int m = wm * 64 + mi * 16 + lr;
      af[mi] = *(const bf16x8*)&As[m * 32 + (kg ^ ((m >> 1) & 3)) * 8];
    }
    #pragma unroll
    for (int ni = 0; ni < 4; ++ni) {
      int n = wn * 64 + ni * 16 + lr;
      bfr[ni] = *(const bf16x8*)&Bs[n * 32 + (kg ^ ((n >> 1) & 3)) * 8];
    }
    #pragma unroll
    for (int mi = 0; mi < 4; ++mi)
      #pragma unroll
      for (int ni = 0; ni < 4; ++ni)
        acc[mi][ni] = __builtin_amdgcn_mfma_f32_16x16x32_bf16(af[mi], bfr[ni], acc[mi][ni], 0, 0, 0);
    __syncthreads();
  }
  #pragma unroll
  for (int ni = 0; ni < 4; ++ni) {
    int col = n0 + wn * 64 + ni * 16 + lr;
    float bv = bias ? bias[col] : 0.f;
    #pragma unroll
    for (int mi = 0; mi < 4; ++mi) {
      #pragma unroll
      for (int r = 0; r < 4; ++r) {
        int row = m0 + wm * 64 + mi * 16 + kg * 4 + r;
        float v = acc[mi][ni][r] + bv;
        if (relu) v = fmaxf(v, 0.f);
        if (resid) v += resid[(size_t)row * ldr + col];
        Cc[(size_t)row * ldc + col] = v;
      }
    }
  }
}

// ---------------- K3: wave-per-token, dot-then-combine attention ----------------
// r12 post-mortem: kv phase was VALU-bound (2048 FMA/lane building kk/vv). Attention is
// linear in K,V, so swap summation order:
//   sim[d,h] = (1/sq32)[ sum_e w[d][e]*(q.K_e)[h] + sum_j scw[d][j]*(q.Wk_bot[j])[h] ]
//   o[c]     = sum_e a_e[h]*V_e[c] + sum_j g_j[h]*Wv_bot[j][c],  a_e = sum_d sm[d]*w[d][e]
// Per-edge scalar dots replace 8x-replicated vector combines (~2.2x less VALU; kk/vv regs freed).
// V rows stashed in 16 uint2 regs during the K loop (fully unrolled -> static indexing, rule #20).
__global__ __launch_bounds__(256) void k3_wave(
    const float* __restrict__ XD,
    const ushort* __restrict__ XKV,
    const float* __restrict__ XQ,
    const int* __restrict__ edges,
    const float* __restrict__ gu,
    const float* __restrict__ xyz,
    const float* __restrict__ Wk, const float* __restrict__ Wv,
    const float* __restrict__ D2, const float* __restrict__ db2,
    float* __restrict__ O)
{
  __shared__ float d2s[1024];
  int t = threadIdx.x;
  for (int i = t; i < 1024; i += 256) {
    int f = i >> 3, d = i & 7;
    d2s[f * 8 + (d ^ (f >> 5))] = D2[i];
  }
  __syncthreads();

  int wvi = t >> 6, lane = t & 63;
  int b = blockIdx.y;
  int n = blockIdx.x * 4 + wvi;
  size_t bn = (size_t)b * NB + n;
  int e = lane >> 2, fq = lane & 3;

  int idx = edges[(bn * 16 + e) * 2];

  // --- h-phase: h[e][d] = db2[d] + sum_f relu(xD[idx[e]][f]) * D2[f][d]
  float acc[8] = {0.f, 0.f, 0.f, 0.f, 0.f, 0.f, 0.f, 0.f};
  const float4* xd4 = (const float4*)(XD + ((size_t)b * NB + idx) * 128 + fq * 32);
  #pragma unroll
  for (int i = 0; i < 8; ++i) {
    float4 xd = xd4[i];
    float xv[4] = {fmaxf(xd.x, 0.f), fmaxf(xd.y, 0.f), fmaxf(xd.z, 0.f), fmaxf(xd.w, 0.f)};
    #pragma unroll
    for (int j = 0; j < 4; ++j) {
      int f = fq * 32 + i * 4 + j;
      #pragma unroll
      for (int d = 0; d < 8; ++d)
        acc[d] += xv[j] * d2s[f * 8 + (d ^ fq)];
    }
  }
  #pragma unroll
  for (int d = 0; d < 8; ++d) {
    acc[d] += __shfl_xor(acc[d], 1);
    acc[d] += __shfl_xor(acc[d], 2);
    acc[d] += db2[d];
  }

  // --- gumbel softmax over e (masks 4..32)
  float w[8];
  #pragma unroll
  for (int d = 0; d < 8; ++d) {
    float u = gu[(bn * 8 + d) * 16 + e];
    float gn = -logf(-logf(u));
    float val = (acc[d] + gn) * 10.0f;   // 1/TAU
    float mx = val;
    mx = fmaxf(mx, __shfl_xor(mx, 4));
    mx = fmaxf(mx, __shfl_xor(mx, 8));
    mx = fmaxf(mx, __shfl_xor(mx, 16));
    mx = fmaxf(mx, __shfl_xor(mx, 32));
    float ex = expf(val - mx);
    float sm = ex;
    sm += __shfl_xor(sm, 4);
    sm += __shfl_xor(sm, 8);
    sm += __shfl_xor(sm, 16);
    sm += __shfl_xor(sm, 32);
    w[d] = ex / sm;
  }

  // --- weighted xyz: lane (e,fq) holds scw[d][fq] (fq<3), identical across e-groups
  float xg = (fq < 3) ? xyz[((size_t)b * NB + idx) * 3 + fq] : 0.f;
  float xo = (fq < 3) ? xyz[bn * 3 + fq] : 0.f;
  float scw[8];
  #pragma unroll
  for (int d = 0; d < 8; ++d) {
    float s = w[d] * xg;
    s += __shfl_xor(s, 4);
    s += __shfl_xor(s, 8);
    s += __shfl_xor(s, 16);
    s += __shfl_xor(s, 32);
    scw[d] = s - xo;   // sum(w)==1 makes the -xyz fold exact
  }

  // --- Phase B: q + per-head dots with Wk_bottom
  float4 q = ((const float4*)(XQ + bn * 256))[lane];
  float qb[3];
  #pragma unroll
  for (int j = 0; j < 3; ++j) {
    float4 wkb = *(const float4*)&Wk[(size_t)(256 + j) * 256 + lane * 4];
    float p = q.x * wkb.x + q.y * wkb.y + q.z * wkb.z + q.w * wkb.w;
    p += __shfl_xor(p, 1);
    p += __shfl_xor(p, 2);
    p += __shfl_xor(p, 4);   // head = 8 lanes
    qb[j] = p;
  }

  // --- Phase C: sim init + K-dot loop (V rows stashed for phase E)
  float sim[8];
  #pragma unroll
  for (int d = 0; d < 8; ++d) {
    float s = 0.f;
    #pragma unroll
    for (int j = 0; j < 3; ++j)
      s += __shfl(scw[d], (lane & ~3) | j) * qb[j];
    sim[d] = s;
  }
  uint2 vreg[16];
  #pragma unroll
  for (int ee = 0; ee < 16; ++ee) {
    int eidx = __shfl(idx, ee * 4);
    const ushort* rE = XKV + ((size_t)b * NB + eidx) * 512;
    uint2 ku = *(const uint2*)(rE + lane * 4);
    vreg[ee] = *(const uint2*)(rE + 256 + lane * 4);
    float k0 = u2f(ku.x << 16), k1 = u2f(ku.x & 0xFFFF0000u);
    float k2 = u2f(ku.y << 16), k3 = u2f(ku.y & 0xFFFF0000u);
    float p = q.x * k0 + q.y * k1 + q.z * k2 + q.w * k3;
    p += __shfl_xor(p, 1);
    p += __shfl_xor(p, 2);
    p += __shfl_xor(p, 4);   // p = (q . K_e) for this lane's head
    #pragma unroll
    for (int d = 0; d < 8; ++d)
      sim[d] += __shfl(w[d], ee * 4) * p;
  }
  #pragma unroll
  for (int d = 0; d < 8; ++d) sim[d] *= 0.17677669529663687f;   // 1/sqrt(32)

  // --- Phase D: softmax over d (per-lane; consistent within head)
  float mx = sim[0];
  #pragma unroll
  for (int d = 1; d < 8; ++d) mx = fmaxf(mx, sim[d]);
  float sm[8], sume = 0.f;
  #pragma unroll
  for (int d = 0; d < 8; ++d) { sm[d] = expf(sim[d] - mx); sume += sm[d]; }
  float inv = 1.f / sume;
  #pragma unroll
  for (int d = 0; d < 8; ++d) sm[d] *= inv;

  // --- Phase E: o = sum_j g_j*Wv_bot[j] + sum_e a_e*V_e
  float4 oc; oc.x = oc.y = oc.z = oc.w = 0.f;
  #pragma unroll
  for (int j = 0; j < 3; ++j) {
    float g = 0.f;
    #pragma unroll
    for (int d = 0; d < 8; ++d)
      g += sm[d] * __shfl(scw[d], (lane & ~3) | j);
    float4 wvb = *(const float4*)&Wv[(size_t)(256 + j) * 256 + lane * 4];
    oc.x += g * wvb.x; oc.y += g * wvb.y; oc.z += g * wvb.z; oc.w += g * wvb.w;
  }
  #pragma unroll
  for (int ee = 0; ee < 16; ++ee) {
    float a = 0.f;
    #pragma unroll
    for (int d = 0; d < 8; ++d)
      a += sm[d] * __shfl(w[d], ee * 4);
    float v0 = u2f(vreg[ee].x << 16), v1 = u2f(vreg[ee].x & 0xFFFF0000u);
    float v2 = u2f(vreg[ee].y << 16), v3 = u2f(vreg[ee].y & 0xFFFF0000u);
    oc.x += a * v0; oc.y += a * v1; oc.z += a * v2; oc.w += a * v3;
  }
  ((float4*)(O + bn * 256))[lane] = oc;
}

// ---------------- K5a: per-row mean/rstd for LN2 ----------------
__global__ __launch_bounds__(256) void k5a_stats(const float* __restrict__ F, float* __restrict__ MRS) {
  int wave = threadIdx.x >> 6, lane = threadIdx.x & 63;
  size_t row = (size_t)blockIdx.x * 4 + wave;
  float4 v4 = *(const float4*)&F[row * 256 + lane * 4];
  float s = v4.x + v4.y + v4.z + v4.w;
  float ss = v4.x * v4.x + v4.y * v4.y + v4.z * v4.z + v4.w * v4.w;
  #pragma unroll
  for (int m = 1; m < 64; m <<= 1) { s += __shfl_xor(s, m); ss += __shfl_xor(ss, m); }
  if (lane == 0) {
    float mean = s * (1.f / 256.f);
    float var = ss * (1.f / 256.f) - mean * mean;
    MRS[row * 2] = mean;
    MRS[row * 2 + 1] = rsqrtf(var + 1e-6f);
  }
}

// ---------------- K7: transpose (B,N,C) -> (B,C,N) ----------------
__global__ __launch_bounds__(256) void k7_transpose(const float* __restrict__ F, float* __restrict__ out) {
  __shared__ float tile[32][33];
  int b = blockIdx.z;
  int c0 = blockIdx.y * 32;
  int n0 = blockIdx.x * 32;
  int t = threadIdx.x;
  int nl = t >> 5, cl = t & 31;
  #pragma unroll
  for (int i = 0; i < 4; ++i) {
    int nn = nl + i * 8;
    tile[nn][cl] = F[((size_t)b * NB + n0 + nn) * 256 + c0 + cl];
  }
  __syncthreads();
  int cl2 = t >> 5, nl2 = t & 31;
  #pragma unroll
  for (int i = 0; i < 4; ++i) {
    int cc = cl2 + i * 8;
    out[((size_t)b * 256 + c0 + cc) * NB + n0 + nl2] = tile[nl2][cc];
  }
}

extern "C" void kernel_launch(void* const* d_in, const int* in_sizes, int n_in,
                              void* d_out, int out_size, void* d_ws, size_t ws_size,
                              hipStream_t stream) {
  const float* xyz      = (const float*)d_in[0];
  const float* features = (const float*)d_in[1];
  const int*   edges    = (const int*)d_in[2];
  const float* gu       = (const float*)d_in[3];
  const float* g1       = (const float*)d_in[4];
  const float* be1      = (const float*)d_in[5];
  const float* Wq       = (const float*)d_in[6];
  const float* Wk       = (const float*)d_in[7];
  const float* Wv       = (const float*)d_in[8];
  const float* Wo       = (const float*)d_in[9];
  const float* g2       = (const float*)d_in[10];
  const float* be2      = (const float*)d_in[11];
  const float* W1       = (const float*)d_in[12];
  const float* bf1      = (const float*)d_in[13];
  const float* W2       = (const float*)d_in[14];
  const float* bf2      = (const float*)d_in[15];
  const float* D1       = (const float*)d_in[16];
  const float* db1      = (const float*)d_in[17];
  const float* D2       = (const float*)d_in[18];
  const float* db2      = (const float*)d_in[19];
  float* out = (float*)d_out;
  float* ws  = (float*)d_ws;

  // ws layout (75.5 MB peak):
  float*  X   = ws;                         // 16384x256 f32 LN1; dead after K2; reused as O
  float*  F   = ws + 4194304;               // 16384x256 feats (in-place chain)
  float*  XD  = ws + 8388608;               // 16384x128 f32 (dead after K3)
  ushort* XKV = (ushort*)(ws + 10485760);   // 16384x512 bf16 (dead after K3)
  float*  XQ  = ws + 14680064;              // 16384x256 f32 (dead after K3)
  float*  O   = X;
  float*  Y1  = ws + 8388608;               // 16384x512 f32 (overwrites XD/XKV after K3)

  // d_out scratch (dead before K7 writes it): bf16 weight packs + MRS
  ushort* WtKVQ = (ushort*)out;             // 768x256
  ushort* WtO   = WtKVQ + 196608;           // 256x256
  ushort* Wt1   = WtO + 65536;              // 512x256
  ushort* Wt2   = Wt1 + 131072;             // 256x512
  ushort* D1hi  = Wt2 + 131072;             // 128x256
  ushort* D1lo  = D1hi + 32768;             // 128x256  (ends at 589824 ushorts)
  float*  MRS   = out + 294912;             // 16384x2

  // K0: pack weights
  wpackT<<<2304, 256, 0, stream>>>(Wk, Wv, Wq, Wo, W1, W2, D1, WtKVQ, WtO, Wt1, Wt2, D1hi, D1lo);

  // K1: transpose + LN1
  k1_ln1<<<dim3(256, 2), 256, 0, stream>>>(features, g1, be1, X, F);

  // K2 fused: XD | XKV | XQ  (one launch, 3 independent GEMMs sharing A=X)
  k2_fused<<<dim3(7, 128), 256, 0, stream>>>(X, D1hi, D1lo, db1, XD, WtKVQ, XKV, XQ);

  // K3: gumbel-softmax + attention -> O
  k3_wave<<<dim3(2048, 2), 256, 0, stream>>>(XD, XKV, XQ, edges, gu, xyz, Wk, Wv, D2, db2, O);

  // K4: feats2 = feats_t + O @ Wo
  gemm_mfma<<<dim3(2, 128), 256, 0, stream>>>(O, 256, WtO, F, 256, 256,
                                              nullptr, 0, F, 256, nullptr, nullptr, nullptr);

  // K5a: LN2 stats
  k5a_stats<<<4096, 256, 0, stream>>>(F, MRS);

  // K5b: Y1 = relu(LN2(feats2) @ W1 + bf1)
  gemm_mfma<<<dim3(4, 128), 256, 0, stream>>>(F, 256, Wt1, Y1, 512, 256,
                                              bf1, 1, nullptr, 0, MRS, g2, be2);

  // K6: feats = feats2 + Y1 @ W2 + bf2
  gemm_mfma<<<dim3(2, 128), 256, 0, stream>>>(Y1, 512, Wt2, F, 256, 512,
                                              bf2, 0, F, 256, nullptr, nullptr, nullptr);

  // K7: transpose to (B, C, N)
  k7_transpose<<<dim3(256, 8, 2), 256, 0, stream>>>(F, out);
}